// Round 1
// 1352.364 us; speedup vs baseline: 1.0976x; 1.0976x over previous
//
#include <hip/hip_runtime.h>
#include <math.h>

constexpr int cS = 512, cD = 1024, cH = 16, cDH = 64;
constexpr int cF1 = 4096, cI = 1024, cE = 8;
constexpr int cT = 4096;
constexpr long long TD = (long long)cT * cD;   // 4M elements
constexpr long long WW = 1048576;              // D*D elements

typedef __attribute__((ext_vector_type(8))) short bfrag;     // 8 bf16
typedef _Float16 f16x8 __attribute__((ext_vector_type(8)));  // 8 fp16
typedef __attribute__((ext_vector_type(4))) float f32x4;

__device__ __forceinline__ float gelu_exact(float x) {
  return 0.5f * x * (1.0f + erff(x * 0.70710678118654752440f));
}
__device__ __forceinline__ unsigned short f2b_rne(float x) {
  union { float f; unsigned u; } v; v.f = x;
  unsigned r = v.u + 0x7fffu + ((v.u >> 16) & 1u);
  return (unsigned short)(r >> 16);
}
// fp16 dual split: v = h + m + eps, |eps| <~ max(|v|*2^-22, 2^-25)
__device__ __forceinline__ void split2(float v, unsigned short& h, unsigned short& m) {
  _Float16 hh = (_Float16)v;
  float r = v - (float)hh;               // exact
  _Float16 mm = (_Float16)r;
  union { _Float16 f; unsigned short u; } a, b;
  a.f = hh; b.f = mm;
  h = a.u; m = b.u;
}
__device__ __forceinline__ void async16(const void* g, void* l) {
  __builtin_amdgcn_global_load_lds(
      (const __attribute__((address_space(1))) unsigned int*)g,
      (__attribute__((address_space(3))) unsigned int*)l, 16, 0, 0);
}

// ---------------------------------------------------------------------------
// fp16 dual-plane MFMA GEMM (fp32-faithful, 3 passes): C = (A@B^T + bias)*alpha
// A: [M,K] as 2 fp16 planes (plane stride aPS) or fp32 (AFP32=1, split on fly)
// B: [N,K] as 2 fp16 planes (plane stride bPS), z-stride sB
// OUT_MODE 0: fp32, z*sC + m*ldc + n
//          2: fp32 [B,S,D], head = zbase+z, n<64
//          4: batched QKV: zz=zbase+z picks tensor; all tensors written dense
//             [B,H,S,dh] split2 into Cp+zz*2*TD (V transposed by separate kernel)
// ---------------------------------------------------------------------------
template<int BM, int BN, int OUT_MODE, int AFP32>
__global__ __launch_bounds__(256) void mgemm2(
    const void* __restrict__ Ap, long long aPS, long long sA, int lda,
    const unsigned short* __restrict__ Bp, long long bPS, long long sB, int ldb,
    const float* __restrict__ bias,
    void* __restrict__ Cp, long long sC, int ldc,
    int K, float alpha, int zbase)
{
  constexpr int WM = BM / 2, WN = BN / 2, AI = WM / 16, BJ = WN / 16;
  constexpr int CA = AFP32 ? 0 : 2 * (BM / 16);
  constexpr int CB = 2 * (BN / 16);
  constexpr int CTOT = CA + CB;
  static_assert(CTOT % 4 == 0, "chunk count");
  constexpr int NCH = CTOT / 4;
  constexpr int FPT = (BM * 32) / 256;   // fp32 A floats per thread (AFP32)
  constexpr int TPR = 256 / BM;          // threads per 32-float A row (AFP32)

  __shared__ unsigned short lA[2][BM * 32];
  __shared__ unsigned short lB[2][BN * 32];

  const int tid = threadIdx.x;
  const int w = tid >> 6, lane = tid & 63;
  const int z = blockIdx.z;
  const int m0 = blockIdx.x * BM, n0 = blockIdx.y * BN;
  const int wm = (w >> 1) * WM, wn = (w & 1) * WN;
  const int lr = lane >> 2, lc8 = (lane & 3) * 8;

  const unsigned short* gsrc[NCH];
  unsigned short* ldst[NCH];
#pragma unroll
  for (int ci = 0; ci < NCH; ++ci) {
    const int c = w + ci * 4;
    if (c < CA) {
      const int p = c / (BM / 16), cc = c % (BM / 16);
      const int row = cc * 16 + lr;
      gsrc[ci] = (const unsigned short*)Ap + p * aPS + (long long)z * sA
               + (long long)(m0 + row) * lda + lc8;
      ldst[ci] = &lA[p][cc * 16 * 32];
    } else {
      const int cb = c - CA;
      const int p = cb / (BN / 16), cc = cb % (BN / 16);
      const int row = cc * 16 + lr;
      gsrc[ci] = Bp + p * bPS + (long long)z * sB + (long long)(n0 + row) * ldb + lc8;
      ldst[ci] = &lB[p][cc * 16 * 32];
    }
  }
  const float* af32 = nullptr;
  int arow = 0, acol = 0;
  if constexpr (AFP32) {
    arow = tid / TPR; acol = (tid % TPR) * FPT;
    af32 = (const float*)Ap + (long long)z * sA + (long long)(m0 + arow) * lda + acol;
  }

  f32x4 acc[AI][BJ];
#pragma unroll
  for (int i = 0; i < AI; ++i)
#pragma unroll
    for (int j = 0; j < BJ; ++j) acc[i][j] = (f32x4){0.f, 0.f, 0.f, 0.f};

  for (int k0 = 0; k0 < K; k0 += 32) {
#pragma unroll
    for (int ci = 0; ci < NCH; ++ci) async16(gsrc[ci] + k0, ldst[ci]);
    if constexpr (AFP32) {
      float vv[FPT];
#pragma unroll
      for (int q4 = 0; q4 < FPT / 4; ++q4)
        *(float4*)&vv[q4 * 4] = *(const float4*)(af32 + k0 + q4 * 4);
      unsigned pk[2][FPT / 2];
#pragma unroll
      for (int q = 0; q < FPT / 2; ++q) {
        unsigned short h0, m0s, h1, m1s;
        split2(vv[2 * q], h0, m0s);
        split2(vv[2 * q + 1], h1, m1s);
        pk[0][q] = (unsigned)h0 | ((unsigned)h1 << 16);
        pk[1][q] = (unsigned)m0s | ((unsigned)m1s << 16);
      }
#pragma unroll
      for (int p = 0; p < 2; ++p) {
        unsigned* d = (unsigned*)&lA[p][arow * 32 + acol];
#pragma unroll
        for (int u = 0; u < FPT / 8; ++u)
          *(uint4*)(d + u * 4) = *(const uint4*)&pk[p][u * 4];
      }
    }
    asm volatile("s_waitcnt vmcnt(0)" ::: "memory");
    __syncthreads();

    f16x8 bf0[BJ], bf1[BJ], af[AI];
#pragma unroll
    for (int j = 0; j < BJ; ++j) {
      bf0[j] = *(const f16x8*)&lB[0][(wn + j * 16 + (lane & 15)) * 32 + (lane >> 4) * 8];
      bf1[j] = *(const f16x8*)&lB[1][(wn + j * 16 + (lane & 15)) * 32 + (lane >> 4) * 8];
    }
#pragma unroll
    for (int i = 0; i < AI; ++i)
      af[i] = *(const f16x8*)&lA[0][(wm + i * 16 + (lane & 15)) * 32 + (lane >> 4) * 8];
#pragma unroll
    for (int i = 0; i < AI; ++i)
#pragma unroll
      for (int j = 0; j < BJ; ++j)
        acc[i][j] = __builtin_amdgcn_mfma_f32_16x16x32_f16(af[i], bf0[j], acc[i][j], 0, 0, 0);
#pragma unroll
    for (int i = 0; i < AI; ++i)
#pragma unroll
      for (int j = 0; j < BJ; ++j)
        acc[i][j] = __builtin_amdgcn_mfma_f32_16x16x32_f16(af[i], bf1[j], acc[i][j], 0, 0, 0);
#pragma unroll
    for (int i = 0; i < AI; ++i)
      af[i] = *(const f16x8*)&lA[1][(wm + i * 16 + (lane & 15)) * 32 + (lane >> 4) * 8];
#pragma unroll
    for (int i = 0; i < AI; ++i)
#pragma unroll
      for (int j = 0; j < BJ; ++j)
        acc[i][j] = __builtin_amdgcn_mfma_f32_16x16x32_f16(af[i], bf0[j], acc[i][j], 0, 0, 0);
    __syncthreads();
  }

  const int zz = zbase + z;
#pragma unroll
  for (int i = 0; i < AI; ++i) {
#pragma unroll
    for (int r = 0; r < 4; ++r) {
      const int gm = m0 + wm + i * 16 + (lane >> 4) * 4 + r;
#pragma unroll
      for (int j = 0; j < BJ; ++j) {
        const int gn = n0 + wn + j * 16 + (lane & 15);
        float v = acc[i][j][r];
        if constexpr (OUT_MODE == 4) {
          v += bias[zz * cD + gn];
          unsigned short* C = (unsigned short*)Cp + (long long)zz * 2 * TD;
          const int b = gm >> 9, s = gm & 511, h = gn >> 6, dd = gn & 63;
          const long long idx = (((long long)(b * cH + h) * cS + s) << 6) + dd;
          unsigned short h_, m_;
          split2(v, h_, m_);
          C[idx] = h_; C[TD + idx] = m_;
        } else {
          if (bias) v += bias[gn];
          v *= alpha;
          long long idx;
          if constexpr (OUT_MODE == 0) {
            idx = (long long)z * sC + (long long)gm * ldc + gn;
          } else {
            const int b = zz >> 4, h = zz & 15;
            idx = ((long long)(b * cS + gm) << 10) + h * 64 + gn;
          }
          ((float*)Cp)[idx] = v;
        }
      }
    }
  }
}

// ---------------------------------------------------------------------------
// V transpose: [B,H,S,dh] 2-plane fp16 -> [B,D,S] 2-plane fp16
// grid (S/128, B*H, 2planes), 256 threads. LDS XOR-swizzle, vector both sides.
// ---------------------------------------------------------------------------
__global__ __launch_bounds__(256) void transposeV(
    const unsigned short* __restrict__ src, unsigned short* __restrict__ dst)
{
  __shared__ unsigned short t[128 * 64];
  const int st = blockIdx.x;                 // s-tile of 128 rows
  const int bh = blockIdx.y;                 // b*16+h
  const long long pl = (long long)blockIdx.z * TD;
  const unsigned short* Sp = src + pl + ((long long)bh * cS + st * 128) * cDH;
  const int tid = threadIdx.x;
  const int r0 = tid >> 3, c0 = (tid & 7) * 8;
#pragma unroll
  for (int i = 0; i < 4; ++i) {
    const int r = r0 + i * 32;
    uint4 v = *(const uint4*)(Sp + (long long)r * cDH + c0);
    *(uint4*)&t[r * 64 + (c0 ^ ((r & 7) << 3))] = v;
  }
  __syncthreads();
  const int dd = tid >> 2;
  unsigned short* Dp = dst + pl + (long long)(bh * cDH + dd) * cS + st * 128;
#pragma unroll
  for (int i = 0; i < 4; ++i) {
    const int s0 = ((tid & 3) + i * 4) * 8;
    alignas(16) unsigned short v[8];
#pragma unroll
    for (int j = 0; j < 8; ++j)
      v[j] = t[(s0 + j) * 64 + (dd ^ (j << 3))];
    *(uint4*)(Dp + s0) = *(const uint4*)v;
  }
}

// ---------------------------------------------------------------------------
// single-plane bf16 MFMA GEMM (MoE): C = act(A@B^T + bias), optional gather/acc
// ---------------------------------------------------------------------------
template<int GATHER>
__global__ __launch_bounds__(256) void mgemm1(
    const unsigned short* __restrict__ A, int lda,
    const unsigned short* __restrict__ Bw, long long sB, int ldb,
    const float* __restrict__ bias, int sBias,
    void* __restrict__ Cp, int ldc,
    int K, int act, int obf, int accum,
    const int* __restrict__ token_list, const int* __restrict__ offsets)
{
  int m0, n0, beg = 0, cnt = 0x7fffffff;
  long long boff = 0;
  if constexpr (GATHER) {
    const int e = blockIdx.y;
    beg = offsets[e]; cnt = offsets[e + 1] - beg;
    m0 = blockIdx.z * 128;
    if (m0 >= cnt) return;
    n0 = blockIdx.x * 128;
    boff = (long long)e * sB;
    if (bias) bias += (long long)e * sBias;
  } else {
    m0 = blockIdx.x * 128; n0 = blockIdx.y * 128;
  }
  __shared__ unsigned short lA[128 * 32];
  __shared__ unsigned short lB[128 * 32];
  const int tid = threadIdx.x, w = tid >> 6, lane = tid & 63;
  const int wm = (w >> 1) * 64, wn = (w & 1) * 64;
  const int lr = lane >> 2, lc8 = (lane & 3) * 8;

  const unsigned short* gsrc[4];
  unsigned short* ldst[4];
#pragma unroll
  for (int ci = 0; ci < 4; ++ci) {
    const int c = w + ci * 4;
    if (c < 8) {
      const int row = c * 16 + lr;
      long long grow;
      if constexpr (GATHER) {
        int mr = m0 + row; if (mr >= cnt) mr = cnt - 1;
        grow = token_list[beg + mr];
      } else grow = m0 + row;
      gsrc[ci] = A + grow * (long long)lda + lc8;
      ldst[ci] = &lA[c * 16 * 32];
    } else {
      const int cc = c - 8;
      const int row = cc * 16 + lr;
      gsrc[ci] = Bw + boff + (long long)(n0 + row) * ldb + lc8;
      ldst[ci] = &lB[cc * 16 * 32];
    }
  }
  f32x4 acc[4][4];
#pragma unroll
  for (int i = 0; i < 4; ++i)
#pragma unroll
    for (int j = 0; j < 4; ++j) acc[i][j] = (f32x4){0.f, 0.f, 0.f, 0.f};

  for (int k0 = 0; k0 < K; k0 += 32) {
#pragma unroll
    for (int ci = 0; ci < 4; ++ci) async16(gsrc[ci] + k0, ldst[ci]);
    asm volatile("s_waitcnt vmcnt(0)" ::: "memory");
    __syncthreads();
    bfrag af[4], bf[4];
#pragma unroll
    for (int i = 0; i < 4; ++i)
      af[i] = *(const bfrag*)&lA[(wm + i * 16 + (lane & 15)) * 32 + (lane >> 4) * 8];
#pragma unroll
    for (int j = 0; j < 4; ++j)
      bf[j] = *(const bfrag*)&lB[(wn + j * 16 + (lane & 15)) * 32 + (lane >> 4) * 8];
#pragma unroll
    for (int i = 0; i < 4; ++i)
#pragma unroll
      for (int j = 0; j < 4; ++j)
        acc[i][j] = __builtin_amdgcn_mfma_f32_16x16x32_bf16(af[i], bf[j], acc[i][j], 0, 0, 0);
    __syncthreads();
  }

#pragma unroll
  for (int i = 0; i < 4; ++i) {
#pragma unroll
    for (int r = 0; r < 4; ++r) {
      const int ml = wm + i * 16 + (lane >> 4) * 4 + r;
      long long orow = 0; bool ok = true;
      if constexpr (GATHER) {
        if (m0 + ml < cnt) orow = token_list[beg + m0 + ml]; else ok = false;
      } else orow = m0 + ml;
      if (ok) {
#pragma unroll
        for (int j = 0; j < 4; ++j) {
          const int gn = n0 + wn + j * 16 + (lane & 15);
          float v = acc[i][j][r];
          if (bias) v += bias[gn];
          if (act) v = gelu_exact(v);
          const long long idx = orow * (long long)ldc + gn;
          if (obf) ((unsigned short*)Cp)[idx] = f2b_rne(v);
          else if (accum) ((float*)Cp)[idx] += v;
          else ((float*)Cp)[idx] = v;
        }
      }
    }
  }
}

// softmax over fp32 scores rows, write P as 2 fp16 planes
__global__ __launch_bounds__(256) void softmax2(
    const float* __restrict__ Sc, unsigned short* __restrict__ P, long long pPS)
{
  const long long row = blockIdx.x;
  const int tid = threadIdx.x;
  const float* pr = Sc + row * cS;
  float2 v = *(const float2*)(pr + tid * 2);
  __shared__ float red[256];
  red[tid] = fmaxf(v.x, v.y);
  __syncthreads();
  for (int st = 128; st > 0; st >>= 1) { if (tid < st) red[tid] = fmaxf(red[tid], red[tid + st]); __syncthreads(); }
  const float M = red[0];
  __syncthreads();
  float e0 = expf(v.x - M), e1 = expf(v.y - M);
  red[tid] = e0 + e1;
  __syncthreads();
  for (int st = 128; st > 0; st >>= 1) { if (tid < st) red[tid] += red[tid + st]; __syncthreads(); }
  const float inv = 1.0f / red[0];
  e0 *= inv; e1 *= inv;
  unsigned short h0, m0s, h1, m1s;
  split2(e0, h0, m0s); split2(e1, h1, m1s);
  const long long o = row * cS + tid * 2;
  *(unsigned*)&P[o] = (unsigned)h0 | ((unsigned)h1 << 16);
  *(unsigned*)&P[pPS + o] = (unsigned)m0s | ((unsigned)m1s << 16);
}

// out = LN(ra + rb*rowscale)*g + be ; optional bf16 copy; optional fused MoE gate
__global__ __launch_bounds__(256) void addln_kernel(
    const float* __restrict__ ra, const float* __restrict__ rb,
    const float* __restrict__ rowscale,
    const float* __restrict__ g, const float* __restrict__ be,
    float* __restrict__ out, unsigned short* __restrict__ out16,
    int gate_on, const int* __restrict__ idxes,
    const float* __restrict__ gw, const float* __restrict__ gb,
    int* __restrict__ gate_idx, float* __restrict__ gate_val, int* __restrict__ counts)
{
  const int row = blockIdx.x, tid = threadIdx.x;
  const long long base = (long long)row * cD + tid * 4;
  const float sc = rowscale ? rowscale[row] : 1.0f;
  float4 va = *(const float4*)(ra + base);
  float4 vb = *(const float4*)(rb + base);
  float v[4] = { va.x + vb.x * sc, va.y + vb.y * sc, va.z + vb.z * sc, va.w + vb.w * sc };
  __shared__ float red[256];
  __shared__ float glog[8];
  red[tid] = v[0] + v[1] + v[2] + v[3];
  __syncthreads();
  for (int st = 128; st > 0; st >>= 1) { if (tid < st) red[tid] += red[tid + st]; __syncthreads(); }
  const float mu = red[0] * (1.0f / cD);
  __syncthreads();
  float vp = 0.f;
#pragma unroll
  for (int i = 0; i < 4; ++i) { float c = v[i] - mu; vp += c * c; }
  red[tid] = vp;
  __syncthreads();
  for (int st = 128; st > 0; st >>= 1) { if (tid < st) red[tid] += red[tid + st]; __syncthreads(); }
  const float rstd = 1.0f / sqrtf(red[0] * (1.0f / cD) + 1e-5f);
  __syncthreads();
  float4 gv = *(const float4*)(g + tid * 4);
  float4 bv = *(const float4*)(be + tid * 4);
  float x[4];
  x[0] = (v[0] - mu) * rstd * gv.x + bv.x;
  x[1] = (v[1] - mu) * rstd * gv.y + bv.y;
  x[2] = (v[2] - mu) * rstd * gv.z + bv.z;
  x[3] = (v[3] - mu) * rstd * gv.w + bv.w;
  if (out) {
    float4 o; o.x = x[0]; o.y = x[1]; o.z = x[2]; o.w = x[3];
    *(float4*)(out + base) = o;
  }
  if (out16) {
    uint2 uu;
    uu.x = (unsigned)f2b_rne(x[0]) | ((unsigned)f2b_rne(x[1]) << 16);
    uu.y = (unsigned)f2b_rne(x[2]) | ((unsigned)f2b_rne(x[3]) << 16);
    *(uint2*)(out16 + base) = uu;
  }
  if (gate_on) {
    const int ds = idxes[row >> 9];
    const float* gwr = gw + (long long)ds * (cE * cD);
    float part[8];
#pragma unroll
    for (int e = 0; e < 8; ++e) {
      float4 wv = *(const float4*)(gwr + e * cD + tid * 4);
      part[e] = x[0] * wv.x + x[1] * wv.y + x[2] * wv.z + x[3] * wv.w;
    }
    for (int e = 0; e < 8; ++e) {
      __syncthreads();
      red[tid] = part[e];
      __syncthreads();
      for (int st = 128; st > 0; st >>= 1) { if (tid < st) red[tid] += red[tid + st]; __syncthreads(); }
      if (tid == 0) glog[e] = red[0] + gb[ds * cE + e];
    }
    if (tid == 0) {
      float m = glog[0]; int arg = 0;
      for (int e = 1; e < 8; ++e) if (glog[e] > m) { m = glog[e]; arg = e; }
      float ssum = 0.f;
      for (int e = 0; e < 8; ++e) ssum += expf(glog[e] - m);
      gate_idx[row] = arg;
      gate_val[row] = 1.0f / ssum;
      atomicAdd(&counts[arg], 1);
    }
  }
}

// 4 fp32 weight tensors (n elems each) -> 2-plane fp16; tensor 0 scaled by sc0
__global__ __launch_bounds__(256) void conv2x4(
    const float* s0, const float* s1, const float* s2, const float* s3,
    unsigned short* dst, int n, float sc0)
{
  const int wsel = blockIdx.y;
  const float* s = (wsel == 0) ? s0 : (wsel == 1) ? s1 : (wsel == 2) ? s2 : s3;
  const float sc = (wsel == 0) ? sc0 : 1.0f;
  unsigned short* d = dst + (long long)wsel * 2 * n;
  const long long i = ((long long)blockIdx.x * 256 + threadIdx.x) * 4;
  if (i >= n) return;
  float4 v = *(const float4*)(s + i);
  float vv[4] = {v.x * sc, v.y * sc, v.z * sc, v.w * sc};
  unsigned short h[4], m[4];
#pragma unroll
  for (int q = 0; q < 4; ++q) split2(vv[q], h[q], m[q]);
  uint2 u;
  u.x = (unsigned)h[0] | ((unsigned)h[1] << 16); u.y = (unsigned)h[2] | ((unsigned)h[3] << 16);
  *(uint2*)&d[i] = u;
  u.x = (unsigned)m[0] | ((unsigned)m[1] << 16); u.y = (unsigned)m[2] | ((unsigned)m[3] << 16);
  *(uint2*)&d[n + i] = u;
}

__global__ __launch_bounds__(256) void conv1(const float* __restrict__ s,
                                             unsigned short* __restrict__ d, long long n)
{
  const long long i = ((long long)blockIdx.x * 256 + threadIdx.x) * 4;
  if (i >= n) return;
  float4 v = *(const float4*)(s + i);
  uint2 u;
  u.x = (unsigned)f2b_rne(v.x) | ((unsigned)f2b_rne(v.y) << 16);
  u.y = (unsigned)f2b_rne(v.z) | ((unsigned)f2b_rne(v.w) << 16);
  *(uint2*)&d[i] = u;
}

// [sa_qb*0.125, sa_kb, sa_vb, ca_qb*0.125, ca_kb, ca_vb] -> 6*cD floats
__global__ void prep_bias(const float* a0, const float* a1, const float* a2,
                          const float* b0, const float* b1, const float* b2,
                          float* dst)
{
  const int i = blockIdx.x * 256 + threadIdx.x;
  const int seg = i >> 10, off = i & 1023;
  const float* srcs[6] = {a0, a1, a2, b0, b1, b2};
  const float sc = (seg == 0 || seg == 3) ? 0.125f : 1.0f;
  dst[i] = srcs[seg][off] * sc;
}

__global__ void scan_kernel(const int* __restrict__ counts, int* __restrict__ offsets,
                            int* __restrict__ cursor)
{
  if (threadIdx.x == 0 && blockIdx.x == 0) {
    int a = 0;
    for (int e = 0; e < cE; ++e) { offsets[e] = a; cursor[e] = a; a += counts[e]; }
    offsets[cE] = a;
  }
}

__global__ __launch_bounds__(256) void scatter_kernel(
    const int* __restrict__ gate_idx, int* __restrict__ cursor, int* __restrict__ token_list)
{
  int t = blockIdx.x * 256 + threadIdx.x;
  if (t < cT) {
    int e = gate_idx[t];
    int slot = atomicAdd(&cursor[e], 1);
    token_list[slot] = t;
  }
}

extern "C" void kernel_launch(void* const* d_in, const int* in_sizes, int n_in,
                              void* d_out, int out_size, void* d_ws, size_t ws_size,
                              hipStream_t stream)
{
  (void)in_sizes; (void)n_in; (void)out_size;
  const float* hidden  = (const float*)d_in[0];
  const float* encoder = (const float*)d_in[1];
  const int*   idxes   = (const int*)d_in[2];
  const float* sa_qw = (const float*)d_in[3];
  const float* sa_qb = (const float*)d_in[4];
  const float* sa_kw = (const float*)d_in[5];
  const float* sa_kb = (const float*)d_in[6];
  const float* sa_vw = (const float*)d_in[7];
  const float* sa_vb = (const float*)d_in[8];
  const float* sa_ow = (const float*)d_in[9];
  const float* sa_ob = (const float*)d_in[10];
  const float* ca_qw = (const float*)d_in[11];
  const float* ca_qb = (const float*)d_in[12];
  const float* ca_kw = (const float*)d_in[13];
  const float* ca_kb = (const float*)d_in[14];
  const float* ca_vw = (const float*)d_in[15];
  const float* ca_vb = (const float*)d_in[16];
  const float* ca_ow = (const float*)d_in[17];
  const float* ca_ob = (const float*)d_in[18];
  const float* sa_ln_g = (const float*)d_in[19];
  const float* sa_ln_b = (const float*)d_in[20];
  const float* ca_ln_g = (const float*)d_in[21];
  const float* ca_ln_b = (const float*)d_in[22];
  const float* fin_ln_g = (const float*)d_in[23];
  const float* fin_ln_b = (const float*)d_in[24];
  const float* fc1_w = (const float*)d_in[25];
  const float* fc1_b = (const float*)d_in[26];
  const float* fc2_w = (const float*)d_in[27];
  const float* fc2_b = (const float*)d_in[28];
  const float* exp1_w = (const float*)d_in[29];
  const float* exp1_b = (const float*)d_in[30];
  const float* exp2_w = (const float*)d_in[31];
  const float* gate_w = (const float*)d_in[32];
  const float* gate_b = (const float*)d_in[33];
  float* out = (float*)d_out;

  // ---- workspace layout ----
  size_t off = 0;
  auto alloc = [&](size_t bytes) {
    void* p = (char*)d_ws + off;
    off += (bytes + 255) & ~(size_t)255;
    return p;
  };
  unsigned short* wbuf = (unsigned short*)alloc(4ll * 2 * WW * 2);   // 16 MB (QKV+O planes / MoE weights)
  unsigned short* QKVs = (unsigned short*)alloc(4ll * 2 * TD * 2);   // 64 MB (Q,K,V,VT dual planes)
  float* attnO = (float*)alloc(TD * 4);                              // 16 MB (also h1 region)
  float* hsa   = (float*)alloc(TD * 4);                              // 16 MB
  float* biasb = (float*)alloc(6 * cD * 4);
  float* gate_val = (float*)alloc(cT * 4);
  int* gate_idx   = (int*)alloc(cT * 4);
  int* token_list = (int*)alloc(cT * 4);
  int* ctl        = (int*)alloc(64 * 4);
  int* counts  = ctl;
  int* offsets = ctl + 16;
  int* cursor  = ctl + 32;
  const size_t off_x = off;
  float* xbuf = (float*)alloc(TD * 4);                               // 16 MB (score region start)
  unsigned short* x16 = (unsigned short*)alloc(TD * 2);              // 8 MB

  // score region = [off_x .. ws end), live only during attention phases
  long long region_bytes = (long long)ws_size - (long long)off_x;
  long long perz = (long long)cS * cS * 8;     // 4B scores + 2*2B P planes
  int ZB = (int)(region_bytes / perz);
  if (ZB < 1) ZB = 1;
  if (ZB > 128) ZB = 128;
  float* scoresF = (float*)((char*)d_ws + off_x);
  unsigned short* Pp = (unsigned short*)((char*)d_ws + off_x + (long long)ZB * cS * cS * 4);
  const long long pPS = (long long)ZB * cS * cS;

  float* OdeltaF = (float*)QKVs;                       // 16 MB, after attention
  unsigned short* h1 = (unsigned short*)attnO;         // 16 MB (2048-token chunks)
  unsigned short* h2 = QKVs;                           // 8 MB
  float* moeF = (float*)(QKVs + 2 * WW * 4);           // 16 MB at QKVs+16MB

  dim3 blk(256);
  hipMemsetAsync(counts, 0, cE * sizeof(int), stream);
  prep_bias<<<dim3(24), blk, 0, stream>>>(sa_qb, sa_kb, sa_vb, ca_qb, ca_kb, ca_vb, biasb);

  auto attention = [&]() {
    for (int zb = 0; zb < 128; zb += ZB) {
      int zc = 128 - zb; if (zc > ZB) zc = ZB;
      // S = Q @ K^T
      mgemm2<128, 128, 0, 0><<<dim3(4, 4, zc), blk, 0, stream>>>(
          QKVs + (long long)zb * (cS * cDH), TD, (long long)cS * cDH, cDH,
          QKVs + 2 * TD + (long long)zb * (cS * cDH), TD, (long long)cS * cDH, cDH,
          nullptr, scoresF, (long long)cS * cS, cS, cDH, 1.0f, 0);
      softmax2<<<dim3(zc * cS), blk, 0, stream>>>(scoresF, Pp, pPS);
      // O = P @ V   (V^T at slot 3: [B,D,S])
      mgemm2<128, 64, 2, 0><<<dim3(4, 1, zc), blk, 0, stream>>>(
          Pp, pPS, (long long)cS * cS, cS,
          QKVs + 6 * TD + (long long)zb * (cDH * cS), TD, (long long)cDH * cS, cS,
          nullptr, attnO, 0, 0, cS, 1.0f, zb);
    }
  };

  // ================= self-attention =================
  conv2x4<<<dim3(1024, 4), blk, 0, stream>>>(sa_qw, sa_kw, sa_vw, sa_ow, wbuf, (int)WW, 0.125f);
  mgemm2<64, 128, 4, 1><<<dim3(64, 8, 3), blk, 0, stream>>>(
      hidden, 0, 0, cD, wbuf, WW, 2 * WW, cD,
      biasb, QKVs, 0, 0, cD, 1.0f, 0);
  transposeV<<<dim3(4, 128, 2), blk, 0, stream>>>(QKVs + 4 * TD, QKVs + 6 * TD);
  attention();
  mgemm2<64, 128, 0, 1><<<dim3(64, 8, 1), blk, 0, stream>>>(
      attnO, 0, 0, cD, wbuf + 6ll * WW, WW, 0, cD,
      sa_ob, OdeltaF, 0, cD, cD, 1.0f, 0);
  addln_kernel<<<dim3(cT), blk, 0, stream>>>(
      hidden, OdeltaF, nullptr, sa_ln_g, sa_ln_b, hsa, nullptr,
      0, nullptr, nullptr, nullptr, nullptr, nullptr, nullptr);

  // ================= cross-attention =================
  conv2x4<<<dim3(1024, 4), blk, 0, stream>>>(ca_qw, ca_kw, ca_vw, ca_ow, wbuf, (int)WW, 0.125f);
  mgemm2<64, 128, 4, 1><<<dim3(64, 8, 1), blk, 0, stream>>>(
      hsa, 0, 0, cD, wbuf, WW, 2 * WW, cD,
      biasb + 3 * cD, QKVs, 0, 0, cD, 1.0f, 0);
  mgemm2<64, 128, 4, 1><<<dim3(64, 8, 2), blk, 0, stream>>>(
      encoder, 0, 0, cD, wbuf + 2ll * WW, WW, 2 * WW, cD,
      biasb + 3 * cD, QKVs, 0, 0, cD, 1.0f, 1);
  transposeV<<<dim3(4, 128, 2), blk, 0, stream>>>(QKVs + 4 * TD, QKVs + 6 * TD);
  attention();
  mgemm2<64, 128, 0, 1><<<dim3(64, 8, 1), blk, 0, stream>>>(
      attnO, 0, 0, cD, wbuf + 6ll * WW, WW, 0, cD,
      ca_ob, OdeltaF, 0, cD, cD, 1.0f, 0);
  addln_kernel<<<dim3(cT), blk, 0, stream>>>(
      hsa, OdeltaF, nullptr, ca_ln_g, ca_ln_b, xbuf, x16,
      1, idxes, gate_w, gate_b, gate_idx, gate_val, counts);

  // ================= MoE FFN =================
  scan_kernel<<<dim3(1), dim3(64), 0, stream>>>(counts, offsets, cursor);
  scatter_kernel<<<dim3(16), blk, 0, stream>>>(gate_idx, cursor, token_list);

  unsigned short* wfc1 = wbuf;
  unsigned short* wfc2 = wbuf + 4194304;
  conv1<<<dim3(4096), blk, 0, stream>>>(fc1_w, wfc1, 4194304);
  conv1<<<dim3(4096), blk, 0, stream>>>(fc2_w, wfc2, 4194304);
  for (int tc = 0; tc < cT; tc += 2048) {
    mgemm1<0><<<dim3(16, 32), blk, 0, stream>>>(
        x16 + (long long)tc * cD, cD, wfc1, 0, cD, fc1_b, 0,
        h1, cF1, cD, 1, 1, 0, nullptr, nullptr);
    mgemm1<0><<<dim3(16, 8), blk, 0, stream>>>(
        h1, cF1, wfc2, 0, cF1, fc2_b, 0,
        moeF + (long long)tc * cD, cD, cF1, 0, 0, 0, nullptr, nullptr);
  }
  conv1<<<dim3(8192), blk, 0, stream>>>(exp1_w, wbuf, 8388608);
  mgemm1<1><<<dim3(8, 8, 32), blk, 0, stream>>>(
      x16, cD, wbuf, (long long)cI * cD, cD, exp1_b, cI,
      h2, cI, cD, 1, 1, 0, token_list, offsets);
  conv1<<<dim3(8192), blk, 0, stream>>>(exp2_w, wbuf, 8388608);
  mgemm1<1><<<dim3(8, 8, 32), blk, 0, stream>>>(
      h2, cI, wbuf, (long long)cD * cI, cI, nullptr, 0,
      moeF, cD, cI, 0, 0, 1, token_list, offsets);

  addln_kernel<<<dim3(cT), blk, 0, stream>>>(
      xbuf, moeF, gate_val, fin_ln_g, fin_ln_b, out, nullptr,
      0, nullptr, nullptr, nullptr, nullptr, nullptr, nullptr);
}

// Round 2
// 1207.162 us; speedup vs baseline: 1.2296x; 1.1203x over previous
//
#include <hip/hip_runtime.h>
#include <math.h>

constexpr int cS = 512, cD = 1024, cH = 16, cDH = 64;
constexpr int cF1 = 4096, cI = 1024, cE = 8;
constexpr int cT = 4096;
constexpr long long TD = (long long)cT * cD;   // 4M elements
constexpr long long WW = 1048576;              // D*D elements

typedef __attribute__((ext_vector_type(8))) short bfrag;     // 8 bf16
typedef _Float16 f16x8 __attribute__((ext_vector_type(8)));  // 8 fp16
typedef __attribute__((ext_vector_type(4))) float f32x4;

__device__ __forceinline__ float gelu_exact(float x) {
  return 0.5f * x * (1.0f + erff(x * 0.70710678118654752440f));
}
__device__ __forceinline__ unsigned short f2b_rne(float x) {
  union { float f; unsigned u; } v; v.f = x;
  unsigned r = v.u + 0x7fffu + ((v.u >> 16) & 1u);
  return (unsigned short)(r >> 16);
}
// fp16 dual split: v = h + m + eps, |eps| <~ max(|v|*2^-22, 2^-25)
__device__ __forceinline__ void split2(float v, unsigned short& h, unsigned short& m) {
  _Float16 hh = (_Float16)v;
  float r = v - (float)hh;               // exact
  _Float16 mm = (_Float16)r;
  union { _Float16 f; unsigned short u; } a, b;
  a.f = hh; b.f = mm;
  h = a.u; m = b.u;
}
__device__ __forceinline__ void async16(const void* g, void* l) {
  __builtin_amdgcn_global_load_lds(
      (const __attribute__((address_space(1))) unsigned int*)g,
      (__attribute__((address_space(3))) unsigned int*)l, 16, 0, 0);
}
__device__ __forceinline__ float wsum(float v) {
#pragma unroll
  for (int off = 32; off; off >>= 1) v += __shfl_xor(v, off, 64);
  return v;
}
__device__ __forceinline__ float wmax(float v) {
#pragma unroll
  for (int off = 32; off; off >>= 1) v = fmaxf(v, __shfl_xor(v, off, 64));
  return v;
}

// ---------------------------------------------------------------------------
// fp16 dual-plane MFMA GEMM (fp32-faithful, 3 passes): C = (A@B^T + bias)*alpha
// A: [M,K] 2 fp16 planes (plane stride aPS); B: [N,K] 2 fp16 planes.
// Double-buffered LDS 2-phase pipeline: stage(t+1) overlaps compute(t).
// OUT_MODE 0: fp32, z*sC + m*ldc + n
//          4: batched QKV: zz=zbase+z picks tensor; dense [B,H,S,dh] split2
//          5: dual-fp16 [B,S,D] (plane stride sC), head = zbase+z, n<64
// ---------------------------------------------------------------------------
template<int BM, int BN, int OUT_MODE>
__global__ __launch_bounds__(256) void mgemm2(
    const unsigned short* __restrict__ Ap, long long aPS, long long sA, int lda,
    const unsigned short* __restrict__ Bp, long long bPS, long long sB, int ldb,
    const float* __restrict__ bias,
    void* __restrict__ Cp, long long sC, int ldc,
    int K, float alpha, int zbase)
{
  constexpr int WM = BM / 2, WN = BN / 2, AI = WM / 16, BJ = WN / 16;
  constexpr int CA = 2 * (BM / 16);
  constexpr int CB = 2 * (BN / 16);
  constexpr int CTOT = CA + CB;
  static_assert(CTOT % 4 == 0, "chunk count");
  constexpr int NCH = CTOT / 4;
  constexpr int LT = (BM + BN) * 64;   // ushorts per k-buffer (2 planes * rows * 32)

  __shared__ unsigned short lds[2][LT];

  const int tid = threadIdx.x;
  const int w = tid >> 6, lane = tid & 63;
  const int z = blockIdx.z;
  const int m0 = blockIdx.x * BM, n0 = blockIdx.y * BN;
  const int wm = (w >> 1) * WM, wn = (w & 1) * WN;
  const int lr = lane >> 2, lc8 = (lane & 3) * 8;

  const unsigned short* gsrc[NCH];
  int loff[NCH];
#pragma unroll
  for (int ci = 0; ci < NCH; ++ci) {
    const int c = w + ci * 4;
    if (c < CA) {
      const int p = c / (BM / 16), cc = c % (BM / 16);
      const int row = cc * 16 + lr;
      gsrc[ci] = Ap + p * aPS + (long long)z * sA + (long long)(m0 + row) * lda + lc8;
      loff[ci] = p * (BM * 32) + cc * (16 * 32);
    } else {
      const int cb = c - CA;
      const int p = cb / (BN / 16), cc = cb % (BN / 16);
      const int row = cc * 16 + lr;
      gsrc[ci] = Bp + p * bPS + (long long)z * sB + (long long)(n0 + row) * ldb + lc8;
      loff[ci] = 2 * (BM * 32) + p * (BN * 32) + cc * (16 * 32);
    }
  }

  f32x4 acc[AI][BJ];
#pragma unroll
  for (int i = 0; i < AI; ++i)
#pragma unroll
    for (int j = 0; j < BJ; ++j) acc[i][j] = (f32x4){0.f, 0.f, 0.f, 0.f};

  // prologue: stage tile 0
#pragma unroll
  for (int ci = 0; ci < NCH; ++ci) async16(gsrc[ci], &lds[0][loff[ci]]);
  __syncthreads();   // implicit vmcnt(0): tile 0 landed

  int cur = 0;
  for (int k0 = 32; k0 <= K; k0 += 32) {
    if (k0 < K) {
#pragma unroll
      for (int ci = 0; ci < NCH; ++ci) async16(gsrc[ci] + k0, &lds[cur ^ 1][loff[ci]]);
    }
    const unsigned short* LA0 = &lds[cur][0];
    const unsigned short* LA1 = &lds[cur][BM * 32];
    const unsigned short* LB0 = &lds[cur][2 * (BM * 32)];
    const unsigned short* LB1 = &lds[cur][2 * (BM * 32) + BN * 32];

    f16x8 bf0[BJ], bf1[BJ], af[AI];
#pragma unroll
    for (int j = 0; j < BJ; ++j) {
      bf0[j] = *(const f16x8*)&LB0[(wn + j * 16 + (lane & 15)) * 32 + (lane >> 4) * 8];
      bf1[j] = *(const f16x8*)&LB1[(wn + j * 16 + (lane & 15)) * 32 + (lane >> 4) * 8];
    }
#pragma unroll
    for (int i = 0; i < AI; ++i)
      af[i] = *(const f16x8*)&LA0[(wm + i * 16 + (lane & 15)) * 32 + (lane >> 4) * 8];
#pragma unroll
    for (int i = 0; i < AI; ++i)
#pragma unroll
      for (int j = 0; j < BJ; ++j)
        acc[i][j] = __builtin_amdgcn_mfma_f32_16x16x32_f16(af[i], bf0[j], acc[i][j], 0, 0, 0);
#pragma unroll
    for (int i = 0; i < AI; ++i)
#pragma unroll
      for (int j = 0; j < BJ; ++j)
        acc[i][j] = __builtin_amdgcn_mfma_f32_16x16x32_f16(af[i], bf1[j], acc[i][j], 0, 0, 0);
#pragma unroll
    for (int i = 0; i < AI; ++i)
      af[i] = *(const f16x8*)&LA1[(wm + i * 16 + (lane & 15)) * 32 + (lane >> 4) * 8];
#pragma unroll
    for (int i = 0; i < AI; ++i)
#pragma unroll
      for (int j = 0; j < BJ; ++j)
        acc[i][j] = __builtin_amdgcn_mfma_f32_16x16x32_f16(af[i], bf0[j], acc[i][j], 0, 0, 0);
    __syncthreads();   // drains stage(t+1), syncs reads of lds[cur]
    cur ^= 1;
  }

  const int zz = zbase + z;
#pragma unroll
  for (int i = 0; i < AI; ++i) {
#pragma unroll
    for (int r = 0; r < 4; ++r) {
      const int gm = m0 + wm + i * 16 + (lane >> 4) * 4 + r;
#pragma unroll
      for (int j = 0; j < BJ; ++j) {
        const int gn = n0 + wn + j * 16 + (lane & 15);
        float v = acc[i][j][r];
        if constexpr (OUT_MODE == 4) {
          v += bias[zz * cD + gn];
          unsigned short* C = (unsigned short*)Cp + (long long)zz * 2 * TD;
          const int b = gm >> 9, s = gm & 511, h = gn >> 6, dd = gn & 63;
          const long long idx = (((long long)(b * cH + h) * cS + s) << 6) + dd;
          unsigned short h_, m_;
          split2(v, h_, m_);
          C[idx] = h_; C[TD + idx] = m_;
        } else if constexpr (OUT_MODE == 5) {
          const int b = zz >> 4, h = zz & 15;
          const long long idx = ((long long)(b * cS + gm) << 10) + h * 64 + gn;
          unsigned short h_, m_;
          split2(v, h_, m_);
          ((unsigned short*)Cp)[idx] = h_;
          ((unsigned short*)Cp)[sC + idx] = m_;
        } else {
          if (bias) v += bias[gn];
          v *= alpha;
          const long long idx = (long long)z * sC + (long long)gm * ldc + gn;
          ((float*)Cp)[idx] = v;
        }
      }
    }
  }
}

// ---------------------------------------------------------------------------
// V transpose: [B,H,S,dh] 2-plane fp16 -> [B,D,S] 2-plane fp16
// ---------------------------------------------------------------------------
__global__ __launch_bounds__(256) void transposeV(
    const unsigned short* __restrict__ src, unsigned short* __restrict__ dst)
{
  __shared__ unsigned short t[128 * 64];
  const int st = blockIdx.x;                 // s-tile of 128 rows
  const int bh = blockIdx.y;                 // b*16+h
  const long long pl = (long long)blockIdx.z * TD;
  const unsigned short* Sp = src + pl + ((long long)bh * cS + st * 128) * cDH;
  const int tid = threadIdx.x;
  const int r0 = tid >> 3, c0 = (tid & 7) * 8;
#pragma unroll
  for (int i = 0; i < 4; ++i) {
    const int r = r0 + i * 32;
    uint4 v = *(const uint4*)(Sp + (long long)r * cDH + c0);
    *(uint4*)&t[r * 64 + (c0 ^ ((r & 7) << 3))] = v;
  }
  __syncthreads();
  const int dd = tid >> 2;
  unsigned short* Dp = dst + pl + (long long)(bh * cDH + dd) * cS + st * 128;
#pragma unroll
  for (int i = 0; i < 4; ++i) {
    const int s0 = ((tid & 3) + i * 4) * 8;
    alignas(16) unsigned short v[8];
#pragma unroll
    for (int j = 0; j < 8; ++j)
      v[j] = t[(s0 + j) * 64 + (dd ^ (j << 3))];
    *(uint4*)(Dp + s0) = *(const uint4*)v;
  }
}

// ---------------------------------------------------------------------------
// single-plane bf16 MFMA GEMM (MoE): C = act(A@B^T + bias), gather/acc options
// Double-buffered LDS 2-phase pipeline.
// ---------------------------------------------------------------------------
template<int GATHER>
__global__ __launch_bounds__(256) void mgemm1(
    const unsigned short* __restrict__ A, int lda,
    const unsigned short* __restrict__ Bw, long long sB, int ldb,
    const float* __restrict__ bias, int sBias,
    void* __restrict__ Cp, int ldc,
    int K, int act, int obf, int accum,
    const int* __restrict__ token_list, const int* __restrict__ offsets)
{
  int m0, n0, beg = 0, cnt = 0x7fffffff;
  long long boff = 0;
  if constexpr (GATHER) {
    const int e = blockIdx.y;
    beg = offsets[e]; cnt = offsets[e + 1] - beg;
    m0 = blockIdx.z * 128;
    if (m0 >= cnt) return;
    n0 = blockIdx.x * 128;
    boff = (long long)e * sB;
    if (bias) bias += (long long)e * sBias;
  } else {
    m0 = blockIdx.x * 128; n0 = blockIdx.y * 128;
  }
  __shared__ unsigned short lds[2][256 * 32];
  const int tid = threadIdx.x, w = tid >> 6, lane = tid & 63;
  const int wm = (w >> 1) * 64, wn = (w & 1) * 64;
  const int lr = lane >> 2, lc8 = (lane & 3) * 8;

  const unsigned short* gsrc[4];
  int loff[4];
#pragma unroll
  for (int ci = 0; ci < 4; ++ci) {
    const int c = w + ci * 4;
    if (c < 8) {
      const int row = c * 16 + lr;
      long long grow;
      if constexpr (GATHER) {
        int mr = m0 + row; if (mr >= cnt) mr = cnt - 1;
        grow = token_list[beg + mr];
      } else grow = m0 + row;
      gsrc[ci] = A + grow * (long long)lda + lc8;
      loff[ci] = c * (16 * 32);
    } else {
      const int cc = c - 8;
      const int row = cc * 16 + lr;
      gsrc[ci] = Bw + boff + (long long)(n0 + row) * ldb + lc8;
      loff[ci] = 128 * 32 + cc * (16 * 32);
    }
  }
  f32x4 acc[4][4];
#pragma unroll
  for (int i = 0; i < 4; ++i)
#pragma unroll
    for (int j = 0; j < 4; ++j) acc[i][j] = (f32x4){0.f, 0.f, 0.f, 0.f};

#pragma unroll
  for (int ci = 0; ci < 4; ++ci) async16(gsrc[ci], &lds[0][loff[ci]]);
  __syncthreads();

  int cur = 0;
  for (int k0 = 32; k0 <= K; k0 += 32) {
    if (k0 < K) {
#pragma unroll
      for (int ci = 0; ci < 4; ++ci) async16(gsrc[ci] + k0, &lds[cur ^ 1][loff[ci]]);
    }
    const unsigned short* lA = &lds[cur][0];
    const unsigned short* lB = &lds[cur][128 * 32];
    bfrag af[4], bf[4];
#pragma unroll
    for (int i = 0; i < 4; ++i)
      af[i] = *(const bfrag*)&lA[(wm + i * 16 + (lane & 15)) * 32 + (lane >> 4) * 8];
#pragma unroll
    for (int j = 0; j < 4; ++j)
      bf[j] = *(const bfrag*)&lB[(wn + j * 16 + (lane & 15)) * 32 + (lane >> 4) * 8];
#pragma unroll
    for (int i = 0; i < 4; ++i)
#pragma unroll
      for (int j = 0; j < 4; ++j)
        acc[i][j] = __builtin_amdgcn_mfma_f32_16x16x32_bf16(af[i], bf[j], acc[i][j], 0, 0, 0);
    __syncthreads();
    cur ^= 1;
  }

#pragma unroll
  for (int i = 0; i < 4; ++i) {
#pragma unroll
    for (int r = 0; r < 4; ++r) {
      const int ml = wm + i * 16 + (lane >> 4) * 4 + r;
      long long orow = 0; bool ok = true;
      if constexpr (GATHER) {
        if (m0 + ml < cnt) orow = token_list[beg + m0 + ml]; else ok = false;
      } else orow = m0 + ml;
      if (ok) {
#pragma unroll
        for (int j = 0; j < 4; ++j) {
          const int gn = n0 + wn + j * 16 + (lane & 15);
          float v = acc[i][j][r];
          if (bias) v += bias[gn];
          if (act) v = gelu_exact(v);
          const long long idx = orow * (long long)ldc + gn;
          if (obf) ((unsigned short*)Cp)[idx] = f2b_rne(v);
          else if (accum) ((float*)Cp)[idx] += v;
          else ((float*)Cp)[idx] = v;
        }
      }
    }
  }
}

// softmax: one wave per row (512 floats, 8/lane), barrier-free, dual-fp16 out
__global__ __launch_bounds__(256) void softmax2(
    const float* __restrict__ Sc, unsigned short* __restrict__ P, long long pPS)
{
  const int w = threadIdx.x >> 6, lane = threadIdx.x & 63;
  const long long row = (long long)blockIdx.x * 4 + w;
  const float* pr = Sc + row * cS + lane * 8;
  float4 a = *(const float4*)pr;
  float4 b = *(const float4*)(pr + 4);
  float e[8] = {a.x, a.y, a.z, a.w, b.x, b.y, b.z, b.w};
  float m = e[0];
#pragma unroll
  for (int q = 1; q < 8; ++q) m = fmaxf(m, e[q]);
  m = wmax(m);
  float s = 0.f;
#pragma unroll
  for (int q = 0; q < 8; ++q) { e[q] = expf(e[q] - m); s += e[q]; }
  s = wsum(s);
  const float inv = 1.0f / s;
  unsigned h[4], mm[4];
#pragma unroll
  for (int q = 0; q < 4; ++q) {
    unsigned short h0, m0s, h1, m1s;
    split2(e[2 * q] * inv, h0, m0s);
    split2(e[2 * q + 1] * inv, h1, m1s);
    h[q] = (unsigned)h0 | ((unsigned)h1 << 16);
    mm[q] = (unsigned)m0s | ((unsigned)m1s << 16);
  }
  const long long o = row * cS + lane * 8;
  *(uint4*)&P[o] = *(const uint4*)h;
  *(uint4*)&P[pPS + o] = *(const uint4*)mm;
}

// out = LN(ra + rb*rowscale)*g + be ; one WAVE per row (16 elem/lane),
// barrier-free; optional bf16 copy, dual-fp16 copy, fused MoE gate.
__global__ __launch_bounds__(256) void addln_kernel(
    const float* __restrict__ ra, const float* __restrict__ rb,
    const float* __restrict__ rowscale,
    const float* __restrict__ g, const float* __restrict__ be,
    float* __restrict__ out, unsigned short* __restrict__ out16,
    unsigned short* __restrict__ out2p,
    int gate_on, const int* __restrict__ idxes,
    const float* __restrict__ gw, const float* __restrict__ gb,
    int* __restrict__ gate_idx, float* __restrict__ gate_val, int* __restrict__ counts)
{
  const int w = threadIdx.x >> 6, lane = threadIdx.x & 63;
  const int row = blockIdx.x * 4 + w;
  const long long base = (long long)row * cD + lane * 16;
  const float sc = rowscale ? rowscale[row] : 1.0f;
  float v[16];
#pragma unroll
  for (int q = 0; q < 4; ++q) {
    float4 a = *(const float4*)(ra + base + q * 4);
    float4 b = *(const float4*)(rb + base + q * 4);
    v[q * 4 + 0] = a.x + b.x * sc; v[q * 4 + 1] = a.y + b.y * sc;
    v[q * 4 + 2] = a.z + b.z * sc; v[q * 4 + 3] = a.w + b.w * sc;
  }
  float s = 0.f;
#pragma unroll
  for (int q = 0; q < 16; ++q) s += v[q];
  const float mu = wsum(s) * (1.0f / cD);
  float vp = 0.f;
#pragma unroll
  for (int q = 0; q < 16; ++q) { float c = v[q] - mu; vp += c * c; }
  const float rstd = 1.0f / sqrtf(wsum(vp) * (1.0f / cD) + 1e-5f);
  float x[16];
#pragma unroll
  for (int q = 0; q < 4; ++q) {
    float4 gv = *(const float4*)(g + lane * 16 + q * 4);
    float4 bv = *(const float4*)(be + lane * 16 + q * 4);
    x[q * 4 + 0] = (v[q * 4 + 0] - mu) * rstd * gv.x + bv.x;
    x[q * 4 + 1] = (v[q * 4 + 1] - mu) * rstd * gv.y + bv.y;
    x[q * 4 + 2] = (v[q * 4 + 2] - mu) * rstd * gv.z + bv.z;
    x[q * 4 + 3] = (v[q * 4 + 3] - mu) * rstd * gv.w + bv.w;
  }
  if (out) {
#pragma unroll
    for (int q = 0; q < 4; ++q) {
      float4 o; o.x = x[q * 4]; o.y = x[q * 4 + 1]; o.z = x[q * 4 + 2]; o.w = x[q * 4 + 3];
      *(float4*)(out + base + q * 4) = o;
    }
  }
  if (out16) {
    unsigned u[8];
#pragma unroll
    for (int q = 0; q < 8; ++q)
      u[q] = (unsigned)f2b_rne(x[2 * q]) | ((unsigned)f2b_rne(x[2 * q + 1]) << 16);
    *(uint4*)&out16[base] = *(const uint4*)&u[0];
    *(uint4*)&out16[base + 8] = *(const uint4*)&u[4];
  }
  if (out2p) {
    unsigned uh[8], um[8];
#pragma unroll
    for (int q = 0; q < 8; ++q) {
      unsigned short h0, m0s, h1, m1s;
      split2(x[2 * q], h0, m0s);
      split2(x[2 * q + 1], h1, m1s);
      uh[q] = (unsigned)h0 | ((unsigned)h1 << 16);
      um[q] = (unsigned)m0s | ((unsigned)m1s << 16);
    }
    *(uint4*)&out2p[base] = *(const uint4*)&uh[0];
    *(uint4*)&out2p[base + 8] = *(const uint4*)&uh[4];
    *(uint4*)&out2p[TD + base] = *(const uint4*)&um[0];
    *(uint4*)&out2p[TD + base + 8] = *(const uint4*)&um[4];
  }
  if (gate_on) {
    const int ds = idxes[row >> 9];
    const float* gwr = gw + (long long)ds * (cE * cD) + lane * 16;
    float glog[8];
#pragma unroll
    for (int e = 0; e < 8; ++e) {
      float pe = 0.f;
#pragma unroll
      for (int q = 0; q < 4; ++q) {
        float4 wv = *(const float4*)(gwr + e * cD + q * 4);
        pe += x[q * 4] * wv.x + x[q * 4 + 1] * wv.y + x[q * 4 + 2] * wv.z + x[q * 4 + 3] * wv.w;
      }
      glog[e] = wsum(pe);
    }
    if (lane == 0) {
      float m = glog[0] + gb[ds * cE];
      int arg = 0;
      float gl[8];
      gl[0] = m;
#pragma unroll
      for (int e = 1; e < 8; ++e) {
        gl[e] = glog[e] + gb[ds * cE + e];
        if (gl[e] > m) { m = gl[e]; arg = e; }
      }
      float ssum = 0.f;
#pragma unroll
      for (int e = 0; e < 8; ++e) ssum += expf(gl[e] - m);
      gate_idx[row] = arg;
      gate_val[row] = 1.0f / ssum;
      atomicAdd(&counts[arg], 1);
    }
  }
}

// 4 fp32 weight tensors (n elems each) -> 2-plane fp16; tensor 0 scaled by sc0
__global__ __launch_bounds__(256) void conv2x4(
    const float* s0, const float* s1, const float* s2, const float* s3,
    unsigned short* dst, int n, float sc0)
{
  const int wsel = blockIdx.y;
  const float* s = (wsel == 0) ? s0 : (wsel == 1) ? s1 : (wsel == 2) ? s2 : s3;
  const float sc = (wsel == 0) ? sc0 : 1.0f;
  unsigned short* d = dst + (long long)wsel * 2 * n;
  const long long i = ((long long)blockIdx.x * 256 + threadIdx.x) * 4;
  if (i >= n) return;
  float4 v = *(const float4*)(s + i);
  float vv[4] = {v.x * sc, v.y * sc, v.z * sc, v.w * sc};
  unsigned short h[4], m[4];
#pragma unroll
  for (int q = 0; q < 4; ++q) split2(vv[q], h[q], m[q]);
  uint2 u;
  u.x = (unsigned)h[0] | ((unsigned)h[1] << 16); u.y = (unsigned)h[2] | ((unsigned)h[3] << 16);
  *(uint2*)&d[i] = u;
  u.x = (unsigned)m[0] | ((unsigned)m[1] << 16); u.y = (unsigned)m[2] | ((unsigned)m[3] << 16);
  *(uint2*)&d[n + i] = u;
}

// fp32 activations -> 2-plane fp16 (plane stride n)
__global__ __launch_bounds__(256) void conv2p(const float* __restrict__ s,
                                              unsigned short* __restrict__ d, long long n)
{
  const long long i = ((long long)blockIdx.x * 256 + threadIdx.x) * 4;
  if (i >= n) return;
  float4 v = *(const float4*)(s + i);
  unsigned short h[4], m[4];
  split2(v.x, h[0], m[0]); split2(v.y, h[1], m[1]);
  split2(v.z, h[2], m[2]); split2(v.w, h[3], m[3]);
  uint2 u;
  u.x = (unsigned)h[0] | ((unsigned)h[1] << 16); u.y = (unsigned)h[2] | ((unsigned)h[3] << 16);
  *(uint2*)&d[i] = u;
  u.x = (unsigned)m[0] | ((unsigned)m[1] << 16); u.y = (unsigned)m[2] | ((unsigned)m[3] << 16);
  *(uint2*)&d[n + i] = u;
}

__global__ __launch_bounds__(256) void conv1(const float* __restrict__ s,
                                             unsigned short* __restrict__ d, long long n)
{
  const long long i = ((long long)blockIdx.x * 256 + threadIdx.x) * 4;
  if (i >= n) return;
  float4 v = *(const float4*)(s + i);
  uint2 u;
  u.x = (unsigned)f2b_rne(v.x) | ((unsigned)f2b_rne(v.y) << 16);
  u.y = (unsigned)f2b_rne(v.z) | ((unsigned)f2b_rne(v.w) << 16);
  *(uint2*)&d[i] = u;
}

// [sa_qb*0.125, sa_kb, sa_vb, ca_qb*0.125, ca_kb, ca_vb] -> 6*cD floats
__global__ void prep_bias(const float* a0, const float* a1, const float* a2,
                          const float* b0, const float* b1, const float* b2,
                          float* dst)
{
  const int i = blockIdx.x * 256 + threadIdx.x;
  const int seg = i >> 10, off = i & 1023;
  const float* srcs[6] = {a0, a1, a2, b0, b1, b2};
  const float sc = (seg == 0 || seg == 3) ? 0.125f : 1.0f;
  dst[i] = srcs[seg][off] * sc;
}

__global__ void scan_kernel(const int* __restrict__ counts, int* __restrict__ offsets,
                            int* __restrict__ cursor)
{
  if (threadIdx.x == 0 && blockIdx.x == 0) {
    int a = 0;
    for (int e = 0; e < cE; ++e) { offsets[e] = a; cursor[e] = a; a += counts[e]; }
    offsets[cE] = a;
  }
}

__global__ __launch_bounds__(256) void scatter_kernel(
    const int* __restrict__ gate_idx, int* __restrict__ cursor, int* __restrict__ token_list)
{
  int t = blockIdx.x * 256 + threadIdx.x;
  if (t < cT) {
    int e = gate_idx[t];
    int slot = atomicAdd(&cursor[e], 1);
    token_list[slot] = t;
  }
}

extern "C" void kernel_launch(void* const* d_in, const int* in_sizes, int n_in,
                              void* d_out, int out_size, void* d_ws, size_t ws_size,
                              hipStream_t stream)
{
  (void)in_sizes; (void)n_in; (void)out_size;
  const float* hidden  = (const float*)d_in[0];
  const float* encoder = (const float*)d_in[1];
  const int*   idxes   = (const int*)d_in[2];
  const float* sa_qw = (const float*)d_in[3];
  const float* sa_qb = (const float*)d_in[4];
  const float* sa_kw = (const float*)d_in[5];
  const float* sa_kb = (const float*)d_in[6];
  const float* sa_vw = (const float*)d_in[7];
  const float* sa_vb = (const float*)d_in[8];
  const float* sa_ow = (const float*)d_in[9];
  const float* sa_ob = (const float*)d_in[10];
  const float* ca_qw = (const float*)d_in[11];
  const float* ca_qb = (const float*)d_in[12];
  const float* ca_kw = (const float*)d_in[13];
  const float* ca_kb = (const float*)d_in[14];
  const float* ca_vw = (const float*)d_in[15];
  const float* ca_vb = (const float*)d_in[16];
  const float* ca_ow = (const float*)d_in[17];
  const float* ca_ob = (const float*)d_in[18];
  const float* sa_ln_g = (const float*)d_in[19];
  const float* sa_ln_b = (const float*)d_in[20];
  const float* ca_ln_g = (const float*)d_in[21];
  const float* ca_ln_b = (const float*)d_in[22];
  const float* fin_ln_g = (const float*)d_in[23];
  const float* fin_ln_b = (const float*)d_in[24];
  const float* fc1_w = (const float*)d_in[25];
  const float* fc1_b = (const float*)d_in[26];
  const float* fc2_w = (const float*)d_in[27];
  const float* fc2_b = (const float*)d_in[28];
  const float* exp1_w = (const float*)d_in[29];
  const float* exp1_b = (const float*)d_in[30];
  const float* exp2_w = (const float*)d_in[31];
  const float* gate_w = (const float*)d_in[32];
  const float* gate_b = (const float*)d_in[33];
  float* out = (float*)d_out;

  // ---- workspace layout ----
  size_t off = 0;
  auto alloc = [&](size_t bytes) {
    void* p = (char*)d_ws + off;
    off += (bytes + 255) & ~(size_t)255;
    return p;
  };
  unsigned short* wbuf = (unsigned short*)alloc(4ll * 2 * WW * 2);   // 16 MB (weights)
  unsigned short* QKVs = (unsigned short*)alloc(4ll * 2 * TD * 2);   // 64 MB (Q,K,V,VT/A16 slots)
  unsigned short* attnO16 = (unsigned short*)alloc(2ll * TD * 2);    // 16 MB (O dual-fp16 / hsa16 / h1)
  float* hsa   = (float*)alloc(TD * 4);                              // 16 MB
  float* biasb = (float*)alloc(6 * cD * 4);
  float* gate_val = (float*)alloc(cT * 4);
  int* gate_idx   = (int*)alloc(cT * 4);
  int* token_list = (int*)alloc(cT * 4);
  int* ctl        = (int*)alloc(64 * 4);
  int* counts  = ctl;
  int* offsets = ctl + 16;
  int* cursor  = ctl + 32;
  const size_t off_x = off;
  float* xbuf = (float*)alloc(TD * 4);                               // 16 MB (score region start)
  unsigned short* x16 = (unsigned short*)alloc(TD * 2);              // 8 MB

  // score region = [off_x .. ws end), live only during attention phases
  long long region_bytes = (long long)ws_size - (long long)off_x;
  long long perz = (long long)cS * cS * 8;     // 4B scores + 2*2B P planes
  int ZB = (int)(region_bytes / perz);
  if (ZB < 1) ZB = 1;
  if (ZB > 128) ZB = 128;
  float* scoresF = (float*)((char*)d_ws + off_x);
  unsigned short* Pp = (unsigned short*)((char*)d_ws + off_x + (long long)ZB * cS * cS * 4);
  const long long pPS = (long long)ZB * cS * cS;

  // aliases (disjoint lifetimes):
  unsigned short* A16 = QKVs + 6 * TD;                 // slot 3: hidden16/enc16, later VT
  unsigned short* hsa16 = attnO16;                     // dual-fp16 of hsa (post-SA, pre-CA-attn)
  float* OdeltaF = (float*)QKVs;                       // 16 MB (slot 0), after attention
  unsigned short* h1 = attnO16;                        // 16 MB (2048-token chunks)
  unsigned short* h2 = QKVs;                           // 8 MB
  float* moeF = (float*)(QKVs + 2 * WW * 4);           // 16 MB at QKVs+16MB

  dim3 blk(256);
  hipMemsetAsync(counts, 0, cE * sizeof(int), stream);
  prep_bias<<<dim3(24), blk, 0, stream>>>(sa_qb, sa_kb, sa_vb, ca_qb, ca_kb, ca_vb, biasb);

  auto attention = [&]() {
    for (int zb = 0; zb < 128; zb += ZB) {
      int zc = 128 - zb; if (zc > ZB) zc = ZB;
      // S = Q @ K^T
      mgemm2<128, 64, 0><<<dim3(4, 8, zc), blk, 0, stream>>>(
          QKVs + (long long)zb * (cS * cDH), TD, (long long)cS * cDH, cDH,
          QKVs + 2 * TD + (long long)zb * (cS * cDH), TD, (long long)cS * cDH, cDH,
          nullptr, scoresF, (long long)cS * cS, cS, cDH, 1.0f, 0);
      softmax2<<<dim3(zc * cS / 4), blk, 0, stream>>>(scoresF, Pp, pPS);
      // O = P @ V   (V^T at slot 3: [B,D,S]) -> dual-fp16 [B,S,D]
      mgemm2<128, 64, 5><<<dim3(4, 1, zc), blk, 0, stream>>>(
          Pp, pPS, (long long)cS * cS, cS,
          QKVs + 6 * TD + (long long)zb * (cDH * cS), TD, (long long)cDH * cS, cS,
          nullptr, attnO16, TD, 0, cS, 1.0f, zb);
    }
  };

  // ================= self-attention =================
  conv2x4<<<dim3(1024, 4), blk, 0, stream>>>(sa_qw, sa_kw, sa_vw, sa_ow, wbuf, (int)WW, 0.125f);
  conv2p<<<dim3(4096), blk, 0, stream>>>(hidden, A16, TD);
  mgemm2<64, 128, 4><<<dim3(64, 8, 3), blk, 0, stream>>>(
      A16, TD, 0, cD, wbuf, WW, 2 * WW, cD,
      biasb, QKVs, 0, 0, cD, 1.0f, 0);
  transposeV<<<dim3(4, 128, 2), blk, 0, stream>>>(QKVs + 4 * TD, QKVs + 6 * TD);
  attention();
  mgemm2<64, 128, 0><<<dim3(64, 8, 1), blk, 0, stream>>>(
      attnO16, TD, 0, cD, wbuf + 6ll * WW, WW, 0, cD,
      sa_ob, OdeltaF, 0, cD, cD, 1.0f, 0);
  addln_kernel<<<dim3(cT / 4), blk, 0, stream>>>(
      hidden, OdeltaF, nullptr, sa_ln_g, sa_ln_b, hsa, nullptr, hsa16,
      0, nullptr, nullptr, nullptr, nullptr, nullptr, nullptr);

  // ================= cross-attention =================
  conv2x4<<<dim3(1024, 4), blk, 0, stream>>>(ca_qw, ca_kw, ca_vw, ca_ow, wbuf, (int)WW, 0.125f);
  mgemm2<64, 128, 4><<<dim3(64, 8, 1), blk, 0, stream>>>(
      hsa16, TD, 0, cD, wbuf, WW, 2 * WW, cD,
      biasb + 3 * cD, QKVs, 0, 0, cD, 1.0f, 0);
  conv2p<<<dim3(4096), blk, 0, stream>>>(encoder, A16, TD);
  mgemm2<64, 128, 4><<<dim3(64, 8, 2), blk, 0, stream>>>(
      A16, TD, 0, cD, wbuf + 2ll * WW, WW, 2 * WW, cD,
      biasb + 3 * cD, QKVs, 0, 0, cD, 1.0f, 1);
  transposeV<<<dim3(4, 128, 2), blk, 0, stream>>>(QKVs + 4 * TD, QKVs + 6 * TD);
  attention();
  mgemm2<64, 128, 0><<<dim3(64, 8, 1), blk, 0, stream>>>(
      attnO16, TD, 0, cD, wbuf + 6ll * WW, WW, 0, cD,
      ca_ob, OdeltaF, 0, cD, cD, 1.0f, 0);
  addln_kernel<<<dim3(cT / 4), blk, 0, stream>>>(
      hsa, OdeltaF, nullptr, ca_ln_g, ca_ln_b, xbuf, x16, nullptr,
      1, idxes, gate_w, gate_b, gate_idx, gate_val, counts);

  // ================= MoE FFN =================
  scan_kernel<<<dim3(1), dim3(64), 0, stream>>>(counts, offsets, cursor);
  scatter_kernel<<<dim3(16), blk, 0, stream>>>(gate_idx, cursor, token_list);

  unsigned short* wfc1 = wbuf;
  unsigned short* wfc2 = wbuf + 4194304;
  conv1<<<dim3(4096), blk, 0, stream>>>(fc1_w, wfc1, 4194304);
  conv1<<<dim3(4096), blk, 0, stream>>>(fc2_w, wfc2, 4194304);
  for (int tc = 0; tc < cT; tc += 2048) {
    mgemm1<0><<<dim3(16, 32), blk, 0, stream>>>(
        x16 + (long long)tc * cD, cD, wfc1, 0, cD, fc1_b, 0,
        h1, cF1, cD, 1, 1, 0, nullptr, nullptr);
    mgemm1<0><<<dim3(16, 8), blk, 0, stream>>>(
        h1, cF1, wfc2, 0, cF1, fc2_b, 0,
        moeF + (long long)tc * cD, cD, cF1, 0, 0, 0, nullptr, nullptr);
  }
  conv1<<<dim3(8192), blk, 0, stream>>>(exp1_w, wbuf, 8388608);
  mgemm1<1><<<dim3(8, 8, 32), blk, 0, stream>>>(
      x16, cD, wbuf, (long long)cI * cD, cD, exp1_b, cI,
      h2, cI, cD, 1, 1, 0, token_list, offsets);
  conv1<<<dim3(8192), blk, 0, stream>>>(exp2_w, wbuf, 8388608);
  mgemm1<1><<<dim3(8, 8, 32), blk, 0, stream>>>(
      h2, cI, wbuf, (long long)cD * cI, cI, nullptr, 0,
      moeF, cD, cI, 0, 0, 1, token_list, offsets);

  addln_kernel<<<dim3(cT / 4), blk, 0, stream>>>(
      xbuf, moeF, gate_val, fin_ln_g, fin_ln_b, out, nullptr, nullptr,
      0, nullptr, nullptr, nullptr, nullptr, nullptr, nullptr);
}

// Round 3
// 1154.638 us; speedup vs baseline: 1.2856x; 1.0455x over previous
//
#include <hip/hip_runtime.h>
#include <math.h>

constexpr int cS = 512, cD = 1024, cH = 16, cDH = 64;
constexpr int cF1 = 4096, cI = 1024, cE = 8;
constexpr int cT = 4096;
constexpr long long TD = (long long)cT * cD;   // 4M elements
constexpr long long WW = 1048576;              // D*D elements

typedef __attribute__((ext_vector_type(8))) short bfrag;     // 8 bf16
typedef _Float16 f16x8 __attribute__((ext_vector_type(8)));  // 8 fp16
typedef __attribute__((ext_vector_type(4))) float f32x4;

__device__ __forceinline__ float gelu_exact(float x) {
  return 0.5f * x * (1.0f + erff(x * 0.70710678118654752440f));
}
__device__ __forceinline__ unsigned short f2b_rne(float x) {
  union { float f; unsigned u; } v; v.f = x;
  unsigned r = v.u + 0x7fffu + ((v.u >> 16) & 1u);
  return (unsigned short)(r >> 16);
}
// fp16 dual split: v = h + m + eps, |eps| <~ max(|v|*2^-22, 2^-25)
__device__ __forceinline__ void split2(float v, unsigned short& h, unsigned short& m) {
  _Float16 hh = (_Float16)v;
  float r = v - (float)hh;               // exact
  _Float16 mm = (_Float16)r;
  union { _Float16 f; unsigned short u; } a, b;
  a.f = hh; b.f = mm;
  h = a.u; m = b.u;
}
__device__ __forceinline__ void async16(const void* g, void* l) {
  __builtin_amdgcn_global_load_lds(
      (const __attribute__((address_space(1))) unsigned int*)g,
      (__attribute__((address_space(3))) unsigned int*)l, 16, 0, 0);
}
__device__ __forceinline__ float wsum(float v) {
#pragma unroll
  for (int off = 32; off; off >>= 1) v += __shfl_xor(v, off, 64);
  return v;
}
__device__ __forceinline__ float wmax(float v) {
#pragma unroll
  for (int off = 32; off; off >>= 1) v = fmaxf(v, __shfl_xor(v, off, 64));
  return v;
}

// ---------------------------------------------------------------------------
// fp16 dual-plane MFMA GEMM (fp32-faithful, 3 passes): C = (A@B^T + bias)*alpha
// A: [M,K] 2 fp16 planes (plane stride aPS); B: [N,K] 2 fp16 planes.
// NW waves arranged WR rows x (NW/WR) cols; per-wave tile WM x WN.
// Double-buffered LDS 2-phase pipeline: stage(t+1) overlaps compute(t).
// OUT_MODE 0: fp32, z*sC + m*ldc + n
//          4: batched QKV: zz=zbase+z picks tensor; dense [B,H,S,dh] split2
//          5: dual-fp16 [B,S,D] (plane stride sC), head = zbase+z, n<64
// ---------------------------------------------------------------------------
template<int BM, int BN, int NW, int WR, int OUT_MODE>
__global__ __launch_bounds__(NW * 64) void mgemm2(
    const unsigned short* __restrict__ Ap, long long aPS, long long sA, int lda,
    const unsigned short* __restrict__ Bp, long long bPS, long long sB, int ldb,
    const float* __restrict__ bias,
    void* __restrict__ Cp, long long sC, int ldc,
    int K, float alpha, int zbase)
{
  constexpr int WC = NW / WR;
  constexpr int WM = BM / WR, WN = BN / WC, AI = WM / 16, BJ = WN / 16;
  constexpr int CA = 2 * (BM / 16);
  constexpr int CB = 2 * (BN / 16);
  constexpr int CTOT = CA + CB;
  static_assert(CTOT % NW == 0, "chunk count");
  constexpr int NCH = CTOT / NW;
  constexpr int LT = (BM + BN) * 64;   // ushorts per k-buffer (2 planes * rows * 32)

  __shared__ unsigned short lds[2][LT];

  const int tid = threadIdx.x;
  const int w = tid >> 6, lane = tid & 63;
  const int z = blockIdx.z;
  const int m0 = blockIdx.x * BM, n0 = blockIdx.y * BN;
  const int wm = (w / WC) * WM, wn = (w % WC) * WN;
  const int lr = lane >> 2, lc8 = (lane & 3) * 8;

  const unsigned short* gsrc[NCH];
  int loff[NCH];
#pragma unroll
  for (int ci = 0; ci < NCH; ++ci) {
    const int c = w + ci * NW;
    if (c < CA) {
      const int p = c / (BM / 16), cc = c % (BM / 16);
      const int row = cc * 16 + lr;
      gsrc[ci] = Ap + p * aPS + (long long)z * sA + (long long)(m0 + row) * lda + lc8;
      loff[ci] = p * (BM * 32) + cc * (16 * 32);
    } else {
      const int cb = c - CA;
      const int p = cb / (BN / 16), cc = cb % (BN / 16);
      const int row = cc * 16 + lr;
      gsrc[ci] = Bp + p * bPS + (long long)z * sB + (long long)(n0 + row) * ldb + lc8;
      loff[ci] = 2 * (BM * 32) + p * (BN * 32) + cc * (16 * 32);
    }
  }

  f32x4 acc[AI][BJ];
#pragma unroll
  for (int i = 0; i < AI; ++i)
#pragma unroll
    for (int j = 0; j < BJ; ++j) acc[i][j] = (f32x4){0.f, 0.f, 0.f, 0.f};

  // prologue: stage tile 0
#pragma unroll
  for (int ci = 0; ci < NCH; ++ci) async16(gsrc[ci], &lds[0][loff[ci]]);
  __syncthreads();   // implicit vmcnt(0): tile 0 landed

  int cur = 0;
  for (int k0 = 32; k0 <= K; k0 += 32) {
    if (k0 < K) {
#pragma unroll
      for (int ci = 0; ci < NCH; ++ci) async16(gsrc[ci] + k0, &lds[cur ^ 1][loff[ci]]);
    }
    const unsigned short* LA0 = &lds[cur][0];
    const unsigned short* LA1 = &lds[cur][BM * 32];
    const unsigned short* LB0 = &lds[cur][2 * (BM * 32)];
    const unsigned short* LB1 = &lds[cur][2 * (BM * 32) + BN * 32];

    f16x8 bf0[BJ], bf1[BJ], af[AI];
#pragma unroll
    for (int j = 0; j < BJ; ++j) {
      bf0[j] = *(const f16x8*)&LB0[(wn + j * 16 + (lane & 15)) * 32 + (lane >> 4) * 8];
      bf1[j] = *(const f16x8*)&LB1[(wn + j * 16 + (lane & 15)) * 32 + (lane >> 4) * 8];
    }
#pragma unroll
    for (int i = 0; i < AI; ++i)
      af[i] = *(const f16x8*)&LA0[(wm + i * 16 + (lane & 15)) * 32 + (lane >> 4) * 8];
#pragma unroll
    for (int i = 0; i < AI; ++i)
#pragma unroll
      for (int j = 0; j < BJ; ++j)
        acc[i][j] = __builtin_amdgcn_mfma_f32_16x16x32_f16(af[i], bf0[j], acc[i][j], 0, 0, 0);
#pragma unroll
    for (int i = 0; i < AI; ++i)
#pragma unroll
      for (int j = 0; j < BJ; ++j)
        acc[i][j] = __builtin_amdgcn_mfma_f32_16x16x32_f16(af[i], bf1[j], acc[i][j], 0, 0, 0);
#pragma unroll
    for (int i = 0; i < AI; ++i)
      af[i] = *(const f16x8*)&LA1[(wm + i * 16 + (lane & 15)) * 32 + (lane >> 4) * 8];
#pragma unroll
    for (int i = 0; i < AI; ++i)
#pragma unroll
      for (int j = 0; j < BJ; ++j)
        acc[i][j] = __builtin_amdgcn_mfma_f32_16x16x32_f16(af[i], bf0[j], acc[i][j], 0, 0, 0);
    __syncthreads();   // drains stage(t+1), syncs reads of lds[cur]
    cur ^= 1;
  }

  const int zz = zbase + z;
#pragma unroll
  for (int i = 0; i < AI; ++i) {
#pragma unroll
    for (int r = 0; r < 4; ++r) {
      const int gm = m0 + wm + i * 16 + (lane >> 4) * 4 + r;
#pragma unroll
      for (int j = 0; j < BJ; ++j) {
        const int gn = n0 + wn + j * 16 + (lane & 15);
        float v = acc[i][j][r];
        if constexpr (OUT_MODE == 4) {
          v += bias[zz * cD + gn];
          unsigned short* C = (unsigned short*)Cp + (long long)zz * 2 * TD;
          const int b = gm >> 9, s = gm & 511, h = gn >> 6, dd = gn & 63;
          const long long idx = (((long long)(b * cH + h) * cS + s) << 6) + dd;
          unsigned short h_, m_;
          split2(v, h_, m_);
          C[idx] = h_; C[TD + idx] = m_;
        } else if constexpr (OUT_MODE == 5) {
          const int b = zz >> 4, h = zz & 15;
          const long long idx = ((long long)(b * cS + gm) << 10) + h * 64 + gn;
          unsigned short h_, m_;
          split2(v, h_, m_);
          ((unsigned short*)Cp)[idx] = h_;
          ((unsigned short*)Cp)[sC + idx] = m_;
        } else {
          if (bias) v += bias[gn];
          v *= alpha;
          const long long idx = (long long)z * sC + (long long)gm * ldc + gn;
          ((float*)Cp)[idx] = v;
        }
      }
    }
  }
}

// ---------------------------------------------------------------------------
// V transpose: [B,H,S,dh] 2-plane fp16 -> [B,D,S] 2-plane fp16
// ---------------------------------------------------------------------------
__global__ __launch_bounds__(256) void transposeV(
    const unsigned short* __restrict__ src, unsigned short* __restrict__ dst)
{
  __shared__ unsigned short t[128 * 64];
  const int st = blockIdx.x;                 // s-tile of 128 rows
  const int bh = blockIdx.y;                 // b*16+h
  const long long pl = (long long)blockIdx.z * TD;
  const unsigned short* Sp = src + pl + ((long long)bh * cS + st * 128) * cDH;
  const int tid = threadIdx.x;
  const int r0 = tid >> 3, c0 = (tid & 7) * 8;
#pragma unroll
  for (int i = 0; i < 4; ++i) {
    const int r = r0 + i * 32;
    uint4 v = *(const uint4*)(Sp + (long long)r * cDH + c0);
    *(uint4*)&t[r * 64 + (c0 ^ ((r & 7) << 3))] = v;
  }
  __syncthreads();
  const int dd = tid >> 2;
  unsigned short* Dp = dst + pl + (long long)(bh * cDH + dd) * cS + st * 128;
#pragma unroll
  for (int i = 0; i < 4; ++i) {
    const int s0 = ((tid & 3) + i * 4) * 8;
    alignas(16) unsigned short v[8];
#pragma unroll
    for (int j = 0; j < 8; ++j)
      v[j] = t[(s0 + j) * 64 + (dd ^ (j << 3))];
    *(uint4*)(Dp + s0) = *(const uint4*)v;
  }
}

// ---------------------------------------------------------------------------
// single-plane bf16 MFMA GEMM (MoE): C = act(A@B^T + bias), gather/acc options
// Double-buffered LDS 2-phase pipeline.
// ---------------------------------------------------------------------------
template<int GATHER>
__global__ __launch_bounds__(256) void mgemm1(
    const unsigned short* __restrict__ A, int lda,
    const unsigned short* __restrict__ Bw, long long sB, int ldb,
    const float* __restrict__ bias, int sBias,
    void* __restrict__ Cp, int ldc,
    int K, int act, int obf, int accum,
    const int* __restrict__ token_list, const int* __restrict__ offsets)
{
  int m0, n0, beg = 0, cnt = 0x7fffffff;
  long long boff = 0;
  if constexpr (GATHER) {
    const int e = blockIdx.y;
    beg = offsets[e]; cnt = offsets[e + 1] - beg;
    m0 = blockIdx.z * 128;
    if (m0 >= cnt) return;
    n0 = blockIdx.x * 128;
    boff = (long long)e * sB;
    if (bias) bias += (long long)e * sBias;
  } else {
    m0 = blockIdx.x * 128; n0 = blockIdx.y * 128;
  }
  __shared__ unsigned short lds[2][256 * 32];
  const int tid = threadIdx.x, w = tid >> 6, lane = tid & 63;
  const int wm = (w >> 1) * 64, wn = (w & 1) * 64;
  const int lr = lane >> 2, lc8 = (lane & 3) * 8;

  const unsigned short* gsrc[4];
  int loff[4];
#pragma unroll
  for (int ci = 0; ci < 4; ++ci) {
    const int c = w + ci * 4;
    if (c < 8) {
      const int row = c * 16 + lr;
      long long grow;
      if constexpr (GATHER) {
        int mr = m0 + row; if (mr >= cnt) mr = cnt - 1;
        grow = token_list[beg + mr];
      } else grow = m0 + row;
      gsrc[ci] = A + grow * (long long)lda + lc8;
      loff[ci] = c * (16 * 32);
    } else {
      const int cc = c - 8;
      const int row = cc * 16 + lr;
      gsrc[ci] = Bw + boff + (long long)(n0 + row) * ldb + lc8;
      loff[ci] = 128 * 32 + cc * (16 * 32);
    }
  }
  f32x4 acc[4][4];
#pragma unroll
  for (int i = 0; i < 4; ++i)
#pragma unroll
    for (int j = 0; j < 4; ++j) acc[i][j] = (f32x4){0.f, 0.f, 0.f, 0.f};

#pragma unroll
  for (int ci = 0; ci < 4; ++ci) async16(gsrc[ci], &lds[0][loff[ci]]);
  __syncthreads();

  int cur = 0;
  for (int k0 = 32; k0 <= K; k0 += 32) {
    if (k0 < K) {
#pragma unroll
      for (int ci = 0; ci < 4; ++ci) async16(gsrc[ci] + k0, &lds[cur ^ 1][loff[ci]]);
    }
    const unsigned short* lA = &lds[cur][0];
    const unsigned short* lB = &lds[cur][128 * 32];
    bfrag af[4], bf[4];
#pragma unroll
    for (int i = 0; i < 4; ++i)
      af[i] = *(const bfrag*)&lA[(wm + i * 16 + (lane & 15)) * 32 + (lane >> 4) * 8];
#pragma unroll
    for (int j = 0; j < 4; ++j)
      bf[j] = *(const bfrag*)&lB[(wn + j * 16 + (lane & 15)) * 32 + (lane >> 4) * 8];
#pragma unroll
    for (int i = 0; i < 4; ++i)
#pragma unroll
      for (int j = 0; j < 4; ++j)
        acc[i][j] = __builtin_amdgcn_mfma_f32_16x16x32_bf16(af[i], bf[j], acc[i][j], 0, 0, 0);
    __syncthreads();
    cur ^= 1;
  }

#pragma unroll
  for (int i = 0; i < 4; ++i) {
#pragma unroll
    for (int r = 0; r < 4; ++r) {
      const int ml = wm + i * 16 + (lane >> 4) * 4 + r;
      long long orow = 0; bool ok = true;
      if constexpr (GATHER) {
        if (m0 + ml < cnt) orow = token_list[beg + m0 + ml]; else ok = false;
      } else orow = m0 + ml;
      if (ok) {
#pragma unroll
        for (int j = 0; j < 4; ++j) {
          const int gn = n0 + wn + j * 16 + (lane & 15);
          float v = acc[i][j][r];
          if (bias) v += bias[gn];
          if (act) v = gelu_exact(v);
          const long long idx = orow * (long long)ldc + gn;
          if (obf) ((unsigned short*)Cp)[idx] = f2b_rne(v);
          else if (accum) ((float*)Cp)[idx] += v;
          else ((float*)Cp)[idx] = v;
        }
      }
    }
  }
}

// softmax: one wave per row (512 floats, 8/lane), barrier-free, dual-fp16 out
__global__ __launch_bounds__(256) void softmax2(
    const float* __restrict__ Sc, unsigned short* __restrict__ P, long long pPS)
{
  const int w = threadIdx.x >> 6, lane = threadIdx.x & 63;
  const long long row = (long long)blockIdx.x * 4 + w;
  const float* pr = Sc + row * cS + lane * 8;
  float4 a = *(const float4*)pr;
  float4 b = *(const float4*)(pr + 4);
  float e[8] = {a.x, a.y, a.z, a.w, b.x, b.y, b.z, b.w};
  float m = e[0];
#pragma unroll
  for (int q = 1; q < 8; ++q) m = fmaxf(m, e[q]);
  m = wmax(m);
  float s = 0.f;
#pragma unroll
  for (int q = 0; q < 8; ++q) { e[q] = expf(e[q] - m); s += e[q]; }
  s = wsum(s);
  const float inv = 1.0f / s;
  unsigned h[4], mm[4];
#pragma unroll
  for (int q = 0; q < 4; ++q) {
    unsigned short h0, m0s, h1, m1s;
    split2(e[2 * q] * inv, h0, m0s);
    split2(e[2 * q + 1] * inv, h1, m1s);
    h[q] = (unsigned)h0 | ((unsigned)h1 << 16);
    mm[q] = (unsigned)m0s | ((unsigned)m1s << 16);
  }
  const long long o = row * cS + lane * 8;
  *(uint4*)&P[o] = *(const uint4*)h;
  *(uint4*)&P[pPS + o] = *(const uint4*)mm;
}

// out = LN(ra + rb*rowscale)*g + be ; one WAVE per row (16 elem/lane),
// barrier-free; optional bf16 copy, dual-fp16 copy, fused MoE gate.
__global__ __launch_bounds__(256) void addln_kernel(
    const float* __restrict__ ra, const float* __restrict__ rb,
    const float* __restrict__ rowscale,
    const float* __restrict__ g, const float* __restrict__ be,
    float* __restrict__ out, unsigned short* __restrict__ out16,
    unsigned short* __restrict__ out2p,
    int gate_on, const int* __restrict__ idxes,
    const float* __restrict__ gw, const float* __restrict__ gb,
    int* __restrict__ gate_idx, float* __restrict__ gate_val, int* __restrict__ counts)
{
  const int w = threadIdx.x >> 6, lane = threadIdx.x & 63;
  const int row = blockIdx.x * 4 + w;
  const long long base = (long long)row * cD + lane * 16;
  const float sc = rowscale ? rowscale[row] : 1.0f;
  float v[16];
#pragma unroll
  for (int q = 0; q < 4; ++q) {
    float4 a = *(const float4*)(ra + base + q * 4);
    float4 b = *(const float4*)(rb + base + q * 4);
    v[q * 4 + 0] = a.x + b.x * sc; v[q * 4 + 1] = a.y + b.y * sc;
    v[q * 4 + 2] = a.z + b.z * sc; v[q * 4 + 3] = a.w + b.w * sc;
  }
  float s = 0.f;
#pragma unroll
  for (int q = 0; q < 16; ++q) s += v[q];
  const float mu = wsum(s) * (1.0f / cD);
  float vp = 0.f;
#pragma unroll
  for (int q = 0; q < 16; ++q) { float c = v[q] - mu; vp += c * c; }
  const float rstd = 1.0f / sqrtf(wsum(vp) * (1.0f / cD) + 1e-5f);
  float x[16];
#pragma unroll
  for (int q = 0; q < 4; ++q) {
    float4 gv = *(const float4*)(g + lane * 16 + q * 4);
    float4 bv = *(const float4*)(be + lane * 16 + q * 4);
    x[q * 4 + 0] = (v[q * 4 + 0] - mu) * rstd * gv.x + bv.x;
    x[q * 4 + 1] = (v[q * 4 + 1] - mu) * rstd * gv.y + bv.y;
    x[q * 4 + 2] = (v[q * 4 + 2] - mu) * rstd * gv.z + bv.z;
    x[q * 4 + 3] = (v[q * 4 + 3] - mu) * rstd * gv.w + bv.w;
  }
  if (out) {
#pragma unroll
    for (int q = 0; q < 4; ++q) {
      float4 o; o.x = x[q * 4]; o.y = x[q * 4 + 1]; o.z = x[q * 4 + 2]; o.w = x[q * 4 + 3];
      *(float4*)(out + base + q * 4) = o;
    }
  }
  if (out16) {
    unsigned u[8];
#pragma unroll
    for (int q = 0; q < 8; ++q)
      u[q] = (unsigned)f2b_rne(x[2 * q]) | ((unsigned)f2b_rne(x[2 * q + 1]) << 16);
    *(uint4*)&out16[base] = *(const uint4*)&u[0];
    *(uint4*)&out16[base + 8] = *(const uint4*)&u[4];
  }
  if (out2p) {
    unsigned uh[8], um[8];
#pragma unroll
    for (int q = 0; q < 8; ++q) {
      unsigned short h0, m0s, h1, m1s;
      split2(x[2 * q], h0, m0s);
      split2(x[2 * q + 1], h1, m1s);
      uh[q] = (unsigned)h0 | ((unsigned)h1 << 16);
      um[q] = (unsigned)m0s | ((unsigned)m1s << 16);
    }
    *(uint4*)&out2p[base] = *(const uint4*)&uh[0];
    *(uint4*)&out2p[base + 8] = *(const uint4*)&uh[4];
    *(uint4*)&out2p[TD + base] = *(const uint4*)&um[0];
    *(uint4*)&out2p[TD + base + 8] = *(const uint4*)&um[4];
  }
  if (gate_on) {
    const int ds = idxes[row >> 9];
    const float* gwr = gw + (long long)ds * (cE * cD) + lane * 16;
    float glog[8];
#pragma unroll
    for (int e = 0; e < 8; ++e) {
      float pe = 0.f;
#pragma unroll
      for (int q = 0; q < 4; ++q) {
        float4 wv = *(const float4*)(gwr + e * cD + q * 4);
        pe += x[q * 4] * wv.x + x[q * 4 + 1] * wv.y + x[q * 4 + 2] * wv.z + x[q * 4 + 3] * wv.w;
      }
      glog[e] = wsum(pe);
    }
    if (lane == 0) {
      float m = glog[0] + gb[ds * cE];
      int arg = 0;
      float gl[8];
      gl[0] = m;
#pragma unroll
      for (int e = 1; e < 8; ++e) {
        gl[e] = glog[e] + gb[ds * cE + e];
        if (gl[e] > m) { m = gl[e]; arg = e; }
      }
      float ssum = 0.f;
#pragma unroll
      for (int e = 0; e < 8; ++e) ssum += expf(gl[e] - m);
      gate_idx[row] = arg;
      gate_val[row] = 1.0f / ssum;
      atomicAdd(&counts[arg], 1);
    }
  }
}

// 4 fp32 weight tensors (n elems each) -> 2-plane fp16; tensor 0 scaled by sc0
__global__ __launch_bounds__(256) void conv2x4(
    const float* s0, const float* s1, const float* s2, const float* s3,
    unsigned short* dst, int n, float sc0)
{
  const int wsel = blockIdx.y;
  const float* s = (wsel == 0) ? s0 : (wsel == 1) ? s1 : (wsel == 2) ? s2 : s3;
  const float sc = (wsel == 0) ? sc0 : 1.0f;
  unsigned short* d = dst + (long long)wsel * 2 * n;
  const long long i = ((long long)blockIdx.x * 256 + threadIdx.x) * 4;
  if (i >= n) return;
  float4 v = *(const float4*)(s + i);
  float vv[4] = {v.x * sc, v.y * sc, v.z * sc, v.w * sc};
  unsigned short h[4], m[4];
#pragma unroll
  for (int q = 0; q < 4; ++q) split2(vv[q], h[q], m[q]);
  uint2 u;
  u.x = (unsigned)h[0] | ((unsigned)h[1] << 16); u.y = (unsigned)h[2] | ((unsigned)h[3] << 16);
  *(uint2*)&d[i] = u;
  u.x = (unsigned)m[0] | ((unsigned)m[1] << 16); u.y = (unsigned)m[2] | ((unsigned)m[3] << 16);
  *(uint2*)&d[n + i] = u;
}

// fp32 activations -> 2-plane fp16 (plane stride n)
__global__ __launch_bounds__(256) void conv2p(const float* __restrict__ s,
                                              unsigned short* __restrict__ d, long long n)
{
  const long long i = ((long long)blockIdx.x * 256 + threadIdx.x) * 4;
  if (i >= n) return;
  float4 v = *(const float4*)(s + i);
  unsigned short h[4], m[4];
  split2(v.x, h[0], m[0]); split2(v.y, h[1], m[1]);
  split2(v.z, h[2], m[2]); split2(v.w, h[3], m[3]);
  uint2 u;
  u.x = (unsigned)h[0] | ((unsigned)h[1] << 16); u.y = (unsigned)h[2] | ((unsigned)h[3] << 16);
  *(uint2*)&d[i] = u;
  u.x = (unsigned)m[0] | ((unsigned)m[1] << 16); u.y = (unsigned)m[2] | ((unsigned)m[3] << 16);
  *(uint2*)&d[n + i] = u;
}

__global__ __launch_bounds__(256) void conv1(const float* __restrict__ s,
                                             unsigned short* __restrict__ d, long long n)
{
  const long long i = ((long long)blockIdx.x * 256 + threadIdx.x) * 4;
  if (i >= n) return;
  float4 v = *(const float4*)(s + i);
  uint2 u;
  u.x = (unsigned)f2b_rne(v.x) | ((unsigned)f2b_rne(v.y) << 16);
  u.y = (unsigned)f2b_rne(v.z) | ((unsigned)f2b_rne(v.w) << 16);
  *(uint2*)&d[i] = u;
}

// [sa_qb*0.125, sa_kb, sa_vb, ca_qb*0.125, ca_kb, ca_vb] -> 6*cD floats
__global__ void prep_bias(const float* a0, const float* a1, const float* a2,
                          const float* b0, const float* b1, const float* b2,
                          float* dst)
{
  const int i = blockIdx.x * 256 + threadIdx.x;
  const int seg = i >> 10, off = i & 1023;
  const float* srcs[6] = {a0, a1, a2, b0, b1, b2};
  const float sc = (seg == 0 || seg == 3) ? 0.125f : 1.0f;
  dst[i] = srcs[seg][off] * sc;
}

__global__ void scan_kernel(const int* __restrict__ counts, int* __restrict__ offsets,
                            int* __restrict__ cursor)
{
  if (threadIdx.x == 0 && blockIdx.x == 0) {
    int a = 0;
    for (int e = 0; e < cE; ++e) { offsets[e] = a; cursor[e] = a; a += counts[e]; }
    offsets[cE] = a;
  }
}

__global__ __launch_bounds__(256) void scatter_kernel(
    const int* __restrict__ gate_idx, int* __restrict__ cursor, int* __restrict__ token_list)
{
  int t = blockIdx.x * 256 + threadIdx.x;
  if (t < cT) {
    int e = gate_idx[t];
    int slot = atomicAdd(&cursor[e], 1);
    token_list[slot] = t;
  }
}

extern "C" void kernel_launch(void* const* d_in, const int* in_sizes, int n_in,
                              void* d_out, int out_size, void* d_ws, size_t ws_size,
                              hipStream_t stream)
{
  (void)in_sizes; (void)n_in; (void)out_size;
  const float* hidden  = (const float*)d_in[0];
  const float* encoder = (const float*)d_in[1];
  const int*   idxes   = (const int*)d_in[2];
  const float* sa_qw = (const float*)d_in[3];
  const float* sa_qb = (const float*)d_in[4];
  const float* sa_kw = (const float*)d_in[5];
  const float* sa_kb = (const float*)d_in[6];
  const float* sa_vw = (const float*)d_in[7];
  const float* sa_vb = (const float*)d_in[8];
  const float* sa_ow = (const float*)d_in[9];
  const float* sa_ob = (const float*)d_in[10];
  const float* ca_qw = (const float*)d_in[11];
  const float* ca_qb = (const float*)d_in[12];
  const float* ca_kw = (const float*)d_in[13];
  const float* ca_kb = (const float*)d_in[14];
  const float* ca_vw = (const float*)d_in[15];
  const float* ca_vb = (const float*)d_in[16];
  const float* ca_ow = (const float*)d_in[17];
  const float* ca_ob = (const float*)d_in[18];
  const float* sa_ln_g = (const float*)d_in[19];
  const float* sa_ln_b = (const float*)d_in[20];
  const float* ca_ln_g = (const float*)d_in[21];
  const float* ca_ln_b = (const float*)d_in[22];
  const float* fin_ln_g = (const float*)d_in[23];
  const float* fin_ln_b = (const float*)d_in[24];
  const float* fc1_w = (const float*)d_in[25];
  const float* fc1_b = (const float*)d_in[26];
  const float* fc2_w = (const float*)d_in[27];
  const float* fc2_b = (const float*)d_in[28];
  const float* exp1_w = (const float*)d_in[29];
  const float* exp1_b = (const float*)d_in[30];
  const float* exp2_w = (const float*)d_in[31];
  const float* gate_w = (const float*)d_in[32];
  const float* gate_b = (const float*)d_in[33];
  float* out = (float*)d_out;

  // ---- workspace layout ----
  size_t off = 0;
  auto alloc = [&](size_t bytes) {
    void* p = (char*)d_ws + off;
    off += (bytes + 255) & ~(size_t)255;
    return p;
  };
  unsigned short* wbuf = (unsigned short*)alloc(4ll * 2 * WW * 2);   // 16 MB (weights)
  unsigned short* QKVs = (unsigned short*)alloc(4ll * 2 * TD * 2);   // 64 MB (Q,K,V,VT/A16 slots)
  unsigned short* attnO16 = (unsigned short*)alloc(2ll * TD * 2);    // 16 MB (O dual-fp16 / hsa16)
  float* hsa   = (float*)alloc(TD * 4);                              // 16 MB
  float* biasb = (float*)alloc(6 * cD * 4);
  float* gate_val = (float*)alloc(cT * 4);
  int* gate_idx   = (int*)alloc(cT * 4);
  int* token_list = (int*)alloc(cT * 4);
  int* ctl        = (int*)alloc(64 * 4);
  int* counts  = ctl;
  int* offsets = ctl + 16;
  int* cursor  = ctl + 32;
  const size_t off_x = off;
  float* xbuf = (float*)alloc(TD * 4);                               // 16 MB (score region start)
  unsigned short* x16 = (unsigned short*)alloc(TD * 2);              // 8 MB

  // score region = [off_x .. ws end), live only during attention phases
  long long region_bytes = (long long)ws_size - (long long)off_x;
  long long perz = (long long)cS * cS * 8;     // 4B scores + 2*2B P planes
  int ZB = (int)(region_bytes / perz);
  if (ZB < 1) ZB = 1;
  if (ZB > 128) ZB = 128;
  float* scoresF = (float*)((char*)d_ws + off_x);
  unsigned short* Pp = (unsigned short*)((char*)d_ws + off_x + (long long)ZB * cS * cS * 4);
  const long long pPS = (long long)ZB * cS * cS;

  // aliases (disjoint lifetimes):
  unsigned short* A16 = QKVs + 6 * TD;                 // slot 3: hidden16/enc16, later VT
  unsigned short* hsa16 = attnO16;                     // dual-fp16 of hsa (post-SA, pre-CA-attn)
  float* OdeltaF = (float*)QKVs;                       // 16 MB (slot 0), after attention
  unsigned short* h2 = QKVs;                           // 8 MB  (MoE phase)
  float* moeF = (float*)(QKVs + 2 * WW * 4);           // 16 MB at QKVs+16MB
  unsigned short* h1 = QKVs + 16ll * WW;               // 32 MB at QKVs+32MB (full fc1 out)

  dim3 blk(256), blk512(512);
  hipMemsetAsync(counts, 0, cE * sizeof(int), stream);
  prep_bias<<<dim3(24), blk, 0, stream>>>(sa_qb, sa_kb, sa_vb, ca_qb, ca_kb, ca_vb, biasb);

  auto attention = [&]() {
    for (int zb = 0; zb < 128; zb += ZB) {
      int zc = 128 - zb; if (zc > ZB) zc = ZB;
      // S = Q @ K^T
      mgemm2<64, 256, 4, 1, 0><<<dim3(8, 2, zc), blk, 0, stream>>>(
          QKVs + (long long)zb * (cS * cDH), TD, (long long)cS * cDH, cDH,
          QKVs + 2 * TD + (long long)zb * (cS * cDH), TD, (long long)cS * cDH, cDH,
          nullptr, scoresF, (long long)cS * cS, cS, cDH, 1.0f, 0);
      softmax2<<<dim3(zc * cS / 4), blk, 0, stream>>>(scoresF, Pp, pPS);
      // O = P @ V   (V^T at slot 3: [B,D,S]) -> dual-fp16 [B,S,D]
      mgemm2<128, 64, 4, 2, 5><<<dim3(4, 1, zc), blk, 0, stream>>>(
          Pp, pPS, (long long)cS * cS, cS,
          QKVs + 6 * TD + (long long)zb * (cDH * cS), TD, (long long)cDH * cS, cS,
          nullptr, attnO16, TD, 0, cS, 1.0f, zb);
    }
  };

  // ================= self-attention =================
  conv2x4<<<dim3(1024, 4), blk, 0, stream>>>(sa_qw, sa_kw, sa_vw, sa_ow, wbuf, (int)WW, 0.125f);
  conv2p<<<dim3(4096), blk, 0, stream>>>(hidden, A16, TD);
  mgemm2<128, 256, 8, 2, 4><<<dim3(32, 4, 3), blk512, 0, stream>>>(
      A16, TD, 0, cD, wbuf, WW, 2 * WW, cD,
      biasb, QKVs, 0, 0, cD, 1.0f, 0);
  transposeV<<<dim3(4, 128, 2), blk, 0, stream>>>(QKVs + 4 * TD, QKVs + 6 * TD);
  attention();
  mgemm2<64, 256, 4, 1, 0><<<dim3(64, 4, 1), blk, 0, stream>>>(
      attnO16, TD, 0, cD, wbuf + 6ll * WW, WW, 0, cD,
      sa_ob, OdeltaF, 0, cD, cD, 1.0f, 0);
  addln_kernel<<<dim3(cT / 4), blk, 0, stream>>>(
      hidden, OdeltaF, nullptr, sa_ln_g, sa_ln_b, hsa, nullptr, hsa16,
      0, nullptr, nullptr, nullptr, nullptr, nullptr, nullptr);

  // ================= cross-attention =================
  conv2x4<<<dim3(1024, 4), blk, 0, stream>>>(ca_qw, ca_kw, ca_vw, ca_ow, wbuf, (int)WW, 0.125f);
  mgemm2<64, 256, 4, 1, 4><<<dim3(64, 4, 1), blk, 0, stream>>>(
      hsa16, TD, 0, cD, wbuf, WW, 2 * WW, cD,
      biasb + 3 * cD, QKVs, 0, 0, cD, 1.0f, 0);
  conv2p<<<dim3(4096), blk, 0, stream>>>(encoder, A16, TD);
  mgemm2<128, 256, 8, 2, 4><<<dim3(32, 4, 2), blk512, 0, stream>>>(
      A16, TD, 0, cD, wbuf + 2ll * WW, WW, 2 * WW, cD,
      biasb + 3 * cD, QKVs, 0, 0, cD, 1.0f, 1);
  transposeV<<<dim3(4, 128, 2), blk, 0, stream>>>(QKVs + 4 * TD, QKVs + 6 * TD);
  attention();
  mgemm2<64, 256, 4, 1, 0><<<dim3(64, 4, 1), blk, 0, stream>>>(
      attnO16, TD, 0, cD, wbuf + 6ll * WW, WW, 0, cD,
      ca_ob, OdeltaF, 0, cD, cD, 1.0f, 0);
  addln_kernel<<<dim3(cT / 4), blk, 0, stream>>>(
      hsa, OdeltaF, nullptr, ca_ln_g, ca_ln_b, xbuf, x16, nullptr,
      1, idxes, gate_w, gate_b, gate_idx, gate_val, counts);

  // ================= MoE FFN =================
  scan_kernel<<<dim3(1), dim3(64), 0, stream>>>(counts, offsets, cursor);
  scatter_kernel<<<dim3(16), blk, 0, stream>>>(gate_idx, cursor, token_list);

  unsigned short* wfc1 = wbuf;
  unsigned short* wfc2 = wbuf + 4194304;
  conv1<<<dim3(4096), blk, 0, stream>>>(fc1_w, wfc1, 4194304);
  conv1<<<dim3(4096), blk, 0, stream>>>(fc2_w, wfc2, 4194304);
  mgemm1<0><<<dim3(32, 32), blk, 0, stream>>>(
      x16, cD, wfc1, 0, cD, fc1_b, 0,
      h1, cF1, cD, 1, 1, 0, nullptr, nullptr);
  mgemm1<0><<<dim3(32, 8), blk, 0, stream>>>(
      h1, cF1, wfc2, 0, cF1, fc2_b, 0,
      moeF, cD, cF1, 0, 0, 0, nullptr, nullptr);
  conv1<<<dim3(8192), blk, 0, stream>>>(exp1_w, wbuf, 8388608);
  mgemm1<1><<<dim3(8, 8, 32), blk, 0, stream>>>(
      x16, cD, wbuf, (long long)cI * cD, cD, exp1_b, cI,
      h2, cI, cD, 1, 1, 0, token_list, offsets);
  conv1<<<dim3(8192), blk, 0, stream>>>(exp2_w, wbuf, 8388608);
  mgemm1<1><<<dim3(8, 8, 32), blk, 0, stream>>>(
      h2, cI, wbuf, (long long)cD * cI, cI, nullptr, 0,
      moeF, cD, cI, 0, 0, 1, token_list, offsets);

  addln_kernel<<<dim3(cT / 4), blk, 0, stream>>>(
      xbuf, moeF, gate_val, fin_ln_g, fin_ln_b, out, nullptr, nullptr,
      0, nullptr, nullptr, nullptr, nullptr, nullptr, nullptr);
}

// Round 4
// 1125.512 us; speedup vs baseline: 1.3188x; 1.0259x over previous
//
#include <hip/hip_runtime.h>
#include <math.h>

constexpr int cS = 512, cD = 1024, cH = 16, cDH = 64;
constexpr int cF1 = 4096, cI = 1024, cE = 8;
constexpr int cT = 4096;
constexpr long long TD = (long long)cT * cD;   // 4M elements
constexpr long long WW = 1048576;              // D*D elements

typedef __attribute__((ext_vector_type(8))) short bfrag;     // 8 bf16
typedef _Float16 f16x8 __attribute__((ext_vector_type(8)));  // 8 fp16
typedef __attribute__((ext_vector_type(4))) float f32x4;

__device__ __forceinline__ float gelu_exact(float x) {
  return 0.5f * x * (1.0f + erff(x * 0.70710678118654752440f));
}
__device__ __forceinline__ unsigned short f2b_rne(float x) {
  union { float f; unsigned u; } v; v.f = x;
  unsigned r = v.u + 0x7fffu + ((v.u >> 16) & 1u);
  return (unsigned short)(r >> 16);
}
// fp16 dual split: v = h + m + eps, |eps| <~ max(|v|*2^-22, 2^-25)
__device__ __forceinline__ void split2(float v, unsigned short& h, unsigned short& m) {
  _Float16 hh = (_Float16)v;
  float r = v - (float)hh;               // exact
  _Float16 mm = (_Float16)r;
  union { _Float16 f; unsigned short u; } a, b;
  a.f = hh; b.f = mm;
  h = a.u; m = b.u;
}
__device__ __forceinline__ void async16(const void* g, void* l) {
  __builtin_amdgcn_global_load_lds(
      (const __attribute__((address_space(1))) unsigned int*)g,
      (__attribute__((address_space(3))) unsigned int*)l, 16, 0, 0);
}
__device__ __forceinline__ float wsum(float v) {
#pragma unroll
  for (int off = 32; off; off >>= 1) v += __shfl_xor(v, off, 64);
  return v;
}
__device__ __forceinline__ float wmax(float v) {
#pragma unroll
  for (int off = 32; off; off >>= 1) v = fmaxf(v, __shfl_xor(v, off, 64));
  return v;
}
// XOR-swizzled ushort offset of (row R, 16B-col c) within [16][32]-chunked tile.
// Within each 1KB chunk: position p=((R&1)<<2)|c stored at p^((R>>1)&7) in the
// (R>>1) 128B row-pair. 16-lane fragment reads then hit all 32 banks 2x (free).
__device__ __forceinline__ int swzoff(int R, int c) {
  const int r = R & 15;
  return (R >> 4) * 512 + (r >> 1) * 64 + (((((r & 1) << 2) | c) ^ ((r >> 1) & 7)) << 3);
}

// ---------------------------------------------------------------------------
// fp16 dual-plane MFMA GEMM (fp32-faithful, 3 passes): C = (A@B^T + bias)*alpha
// A: [M,K] 2 fp16 planes (plane stride aPS); B: [N,K] 2 fp16 planes.
// NW waves arranged WR rows x (NW/WR) cols; per-wave tile WM x WN.
// Double-buffered LDS 2-phase pipeline; both-sides bank-conflict swizzle.
// OUT_MODE 0: fp32, z*sC + m*ldc + n
//          4: fused QKV: tensor = zbase + (gn>>10); dense [B,H,S,dh] split2
//          5: dual-fp16 [B,S,D] (plane stride sC), head = zbase+z, n<64
// ---------------------------------------------------------------------------
template<int BM, int BN, int NW, int WR, int OUT_MODE>
__global__ __launch_bounds__(NW * 64) void mgemm2(
    const unsigned short* __restrict__ Ap, long long aPS, long long sA, int lda,
    const unsigned short* __restrict__ Bp, long long bPS, long long sB, int ldb,
    const float* __restrict__ bias,
    void* __restrict__ Cp, long long sC, int ldc,
    int K, float alpha, int zbase)
{
  constexpr int WC = NW / WR;
  constexpr int WM = BM / WR, WN = BN / WC, AI = WM / 16, BJ = WN / 16;
  constexpr int CA = 2 * (BM / 16);
  constexpr int CB = 2 * (BN / 16);
  constexpr int CTOT = CA + CB;
  static_assert(CTOT % NW == 0, "chunk count");
  constexpr int NCH = CTOT / NW;
  constexpr int LT = (BM + BN) * 64;   // ushorts per k-buffer (2 planes * rows * 32)

  __shared__ unsigned short lds[2][LT];

  const int tid = threadIdx.x;
  const int w = tid >> 6, lane = tid & 63;
  const int z = blockIdx.z;
  const int m0 = blockIdx.x * BM, n0 = blockIdx.y * BN;
  const int wm = (w / WC) * WM, wn = (w % WC) * WN;
  // staging source pre-swizzle (inverse of swzoff; LDS dest stays linear)
  const int sp = (lane & 7) ^ ((lane >> 3) & 7);
  const int srow = ((lane >> 3) << 1) | (sp >> 2);
  const int scol = (sp & 3) << 3;

  const unsigned short* gsrc[NCH];
  int loff[NCH];
#pragma unroll
  for (int ci = 0; ci < NCH; ++ci) {
    const int c = w + ci * NW;
    if (c < CA) {
      const int p = c / (BM / 16), cc = c % (BM / 16);
      const int row = cc * 16 + srow;
      gsrc[ci] = Ap + p * aPS + (long long)z * sA + (long long)(m0 + row) * lda + scol;
      loff[ci] = p * (BM * 32) + cc * 512;
    } else {
      const int cb = c - CA;
      const int p = cb / (BN / 16), cc = cb % (BN / 16);
      const int row = cc * 16 + srow;
      gsrc[ci] = Bp + p * bPS + (long long)z * sB + (long long)(n0 + row) * ldb + scol;
      loff[ci] = 2 * (BM * 32) + p * (BN * 32) + cc * 512;
    }
  }

  f32x4 acc[AI][BJ];
#pragma unroll
  for (int i = 0; i < AI; ++i)
#pragma unroll
    for (int j = 0; j < BJ; ++j) acc[i][j] = (f32x4){0.f, 0.f, 0.f, 0.f};

  // prologue: stage tile 0
#pragma unroll
  for (int ci = 0; ci < NCH; ++ci) async16(gsrc[ci], &lds[0][loff[ci]]);
  asm volatile("s_waitcnt vmcnt(0)" ::: "memory");
  __syncthreads();

  int cur = 0;
  const int lc = lane >> 4;          // 16B col selector for fragment reads
  for (int k0 = 32; k0 <= K; k0 += 32) {
    if (k0 < K) {
#pragma unroll
      for (int ci = 0; ci < NCH; ++ci) async16(gsrc[ci] + k0, &lds[cur ^ 1][loff[ci]]);
    }
    const unsigned short* LA0 = &lds[cur][0];
    const unsigned short* LA1 = &lds[cur][BM * 32];
    const unsigned short* LB0 = &lds[cur][2 * (BM * 32)];
    const unsigned short* LB1 = &lds[cur][2 * (BM * 32) + BN * 32];

    f16x8 bf0[BJ], bf1[BJ], af[AI];
#pragma unroll
    for (int j = 0; j < BJ; ++j) {
      bf0[j] = *(const f16x8*)&LB0[swzoff(wn + j * 16 + (lane & 15), lc)];
      bf1[j] = *(const f16x8*)&LB1[swzoff(wn + j * 16 + (lane & 15), lc)];
    }
#pragma unroll
    for (int i = 0; i < AI; ++i)
      af[i] = *(const f16x8*)&LA0[swzoff(wm + i * 16 + (lane & 15), lc)];
    __builtin_amdgcn_s_setprio(1);
#pragma unroll
    for (int i = 0; i < AI; ++i)
#pragma unroll
      for (int j = 0; j < BJ; ++j)
        acc[i][j] = __builtin_amdgcn_mfma_f32_16x16x32_f16(af[i], bf0[j], acc[i][j], 0, 0, 0);
#pragma unroll
    for (int i = 0; i < AI; ++i)
#pragma unroll
      for (int j = 0; j < BJ; ++j)
        acc[i][j] = __builtin_amdgcn_mfma_f32_16x16x32_f16(af[i], bf1[j], acc[i][j], 0, 0, 0);
    __builtin_amdgcn_s_setprio(0);
#pragma unroll
    for (int i = 0; i < AI; ++i)
      af[i] = *(const f16x8*)&LA1[swzoff(wm + i * 16 + (lane & 15), lc)];
    __builtin_amdgcn_s_setprio(1);
#pragma unroll
    for (int i = 0; i < AI; ++i)
#pragma unroll
      for (int j = 0; j < BJ; ++j)
        acc[i][j] = __builtin_amdgcn_mfma_f32_16x16x32_f16(af[i], bf0[j], acc[i][j], 0, 0, 0);
    __builtin_amdgcn_s_setprio(0);
    asm volatile("s_waitcnt vmcnt(0)" ::: "memory");
    __syncthreads();   // publishes stage(t+1), closes reads of lds[cur]
    cur ^= 1;
  }

#pragma unroll
  for (int i = 0; i < AI; ++i) {
#pragma unroll
    for (int r = 0; r < 4; ++r) {
      const int gm = m0 + wm + i * 16 + (lane >> 4) * 4 + r;
#pragma unroll
      for (int j = 0; j < BJ; ++j) {
        const int gn = n0 + wn + j * 16 + (lane & 15);
        float v = acc[i][j][r];
        if constexpr (OUT_MODE == 4) {
          const int tsel = gn >> 10, gnn = gn & 1023;
          v += bias[tsel * cD + gnn];
          unsigned short* C = (unsigned short*)Cp + (long long)(zbase + tsel) * 2 * TD;
          const int b = gm >> 9, s = gm & 511, h = gnn >> 6, dd = gnn & 63;
          const long long idx = (((long long)(b * cH + h) * cS + s) << 6) + dd;
          unsigned short h_, m_;
          split2(v, h_, m_);
          C[idx] = h_; C[TD + idx] = m_;
        } else if constexpr (OUT_MODE == 5) {
          const int zz = zbase + z;
          const int b = zz >> 4, h = zz & 15;
          const long long idx = ((long long)(b * cS + gm) << 10) + h * 64 + gn;
          unsigned short h_, m_;
          split2(v, h_, m_);
          ((unsigned short*)Cp)[idx] = h_;
          ((unsigned short*)Cp)[sC + idx] = m_;
        } else {
          if (bias) v += bias[gn];
          v *= alpha;
          const long long idx = (long long)z * sC + (long long)gm * ldc + gn;
          ((float*)Cp)[idx] = v;
        }
      }
    }
  }
}

// ---------------------------------------------------------------------------
// V transpose: [B,H,S,dh] 2-plane fp16 -> [B,D,S] 2-plane fp16
// ---------------------------------------------------------------------------
__global__ __launch_bounds__(256) void transposeV(
    const unsigned short* __restrict__ src, unsigned short* __restrict__ dst)
{
  __shared__ unsigned short t[128 * 64];
  const int st = blockIdx.x;                 // s-tile of 128 rows
  const int bh = blockIdx.y;                 // b*16+h
  const long long pl = (long long)blockIdx.z * TD;
  const unsigned short* Sp = src + pl + ((long long)bh * cS + st * 128) * cDH;
  const int tid = threadIdx.x;
  const int r0 = tid >> 3, c0 = (tid & 7) * 8;
#pragma unroll
  for (int i = 0; i < 4; ++i) {
    const int r = r0 + i * 32;
    uint4 v = *(const uint4*)(Sp + (long long)r * cDH + c0);
    *(uint4*)&t[r * 64 + (c0 ^ ((r & 7) << 3))] = v;
  }
  __syncthreads();
  const int dd = tid >> 2;
  unsigned short* Dp = dst + pl + (long long)(bh * cDH + dd) * cS + st * 128;
#pragma unroll
  for (int i = 0; i < 4; ++i) {
    const int s0 = ((tid & 3) + i * 4) * 8;
    alignas(16) unsigned short v[8];
#pragma unroll
    for (int j = 0; j < 8; ++j)
      v[j] = t[(s0 + j) * 64 + (dd ^ (j << 3))];
    *(uint4*)(Dp + s0) = *(const uint4*)v;
  }
}

// ---------------------------------------------------------------------------
// single-plane bf16 MFMA GEMM (MoE): C = act(A@B^T + bias), gather/acc options
// Double-buffered 2-phase pipeline + swizzle + setprio.
// ---------------------------------------------------------------------------
template<int GATHER>
__global__ __launch_bounds__(256) void mgemm1(
    const unsigned short* __restrict__ A, int lda,
    const unsigned short* __restrict__ Bw, long long sB, int ldb,
    const float* __restrict__ bias, int sBias,
    void* __restrict__ Cp, int ldc,
    int K, int act, int obf, int accum,
    const int* __restrict__ token_list, const int* __restrict__ offsets)
{
  int m0, n0, beg = 0, cnt = 0x7fffffff;
  long long boff = 0;
  if constexpr (GATHER) {
    const int e = blockIdx.y;
    beg = offsets[e]; cnt = offsets[e + 1] - beg;
    m0 = blockIdx.z * 128;
    if (m0 >= cnt) return;
    n0 = blockIdx.x * 128;
    boff = (long long)e * sB;
    if (bias) bias += (long long)e * sBias;
  } else {
    m0 = blockIdx.x * 128; n0 = blockIdx.y * 128;
  }
  __shared__ unsigned short lds[2][256 * 32];
  const int tid = threadIdx.x, w = tid >> 6, lane = tid & 63;
  const int wm = (w >> 1) * 64, wn = (w & 1) * 64;
  const int sp = (lane & 7) ^ ((lane >> 3) & 7);
  const int srow = ((lane >> 3) << 1) | (sp >> 2);
  const int scol = (sp & 3) << 3;

  const unsigned short* gsrc[4];
  int loff[4];
#pragma unroll
  for (int ci = 0; ci < 4; ++ci) {
    const int c = w + ci * 4;
    if (c < 8) {
      const int row = c * 16 + srow;
      long long grow;
      if constexpr (GATHER) {
        int mr = m0 + row; if (mr >= cnt) mr = cnt - 1;
        grow = token_list[beg + mr];
      } else grow = m0 + row;
      gsrc[ci] = A + grow * (long long)lda + scol;
      loff[ci] = c * 512;
    } else {
      const int cc = c - 8;
      const int row = cc * 16 + srow;
      gsrc[ci] = Bw + boff + (long long)(n0 + row) * ldb + scol;
      loff[ci] = 128 * 32 + cc * 512;
    }
  }
  f32x4 acc[4][4];
#pragma unroll
  for (int i = 0; i < 4; ++i)
#pragma unroll
    for (int j = 0; j < 4; ++j) acc[i][j] = (f32x4){0.f, 0.f, 0.f, 0.f};

#pragma unroll
  for (int ci = 0; ci < 4; ++ci) async16(gsrc[ci], &lds[0][loff[ci]]);
  asm volatile("s_waitcnt vmcnt(0)" ::: "memory");
  __syncthreads();

  int cur = 0;
  const int lc = lane >> 4;
  for (int k0 = 32; k0 <= K; k0 += 32) {
    if (k0 < K) {
#pragma unroll
      for (int ci = 0; ci < 4; ++ci) async16(gsrc[ci] + k0, &lds[cur ^ 1][loff[ci]]);
    }
    const unsigned short* lA = &lds[cur][0];
    const unsigned short* lB = &lds[cur][128 * 32];
    bfrag af[4], bf[4];
#pragma unroll
    for (int i = 0; i < 4; ++i)
      af[i] = *(const bfrag*)&lA[swzoff(wm + i * 16 + (lane & 15), lc)];
#pragma unroll
    for (int j = 0; j < 4; ++j)
      bf[j] = *(const bfrag*)&lB[swzoff(wn + j * 16 + (lane & 15), lc)];
    __builtin_amdgcn_s_setprio(1);
#pragma unroll
    for (int i = 0; i < 4; ++i)
#pragma unroll
      for (int j = 0; j < 4; ++j)
        acc[i][j] = __builtin_amdgcn_mfma_f32_16x16x32_bf16(af[i], bf[j], acc[i][j], 0, 0, 0);
    __builtin_amdgcn_s_setprio(0);
    asm volatile("s_waitcnt vmcnt(0)" ::: "memory");
    __syncthreads();
    cur ^= 1;
  }

#pragma unroll
  for (int i = 0; i < 4; ++i) {
#pragma unroll
    for (int r = 0; r < 4; ++r) {
      const int ml = wm + i * 16 + (lane >> 4) * 4 + r;
      long long orow = 0; bool ok = true;
      if constexpr (GATHER) {
        if (m0 + ml < cnt) orow = token_list[beg + m0 + ml]; else ok = false;
      } else orow = m0 + ml;
      if (ok) {
#pragma unroll
        for (int j = 0; j < 4; ++j) {
          const int gn = n0 + wn + j * 16 + (lane & 15);
          float v = acc[i][j][r];
          if (bias) v += bias[gn];
          if (act) v = gelu_exact(v);
          const long long idx = orow * (long long)ldc + gn;
          if (obf) ((unsigned short*)Cp)[idx] = f2b_rne(v);
          else if (accum) ((float*)Cp)[idx] += v;
          else ((float*)Cp)[idx] = v;
        }
      }
    }
  }
}

// softmax: one wave per row (512 floats, 8/lane), barrier-free, dual-fp16 out
__global__ __launch_bounds__(256) void softmax2(
    const float* __restrict__ Sc, unsigned short* __restrict__ P, long long pPS)
{
  const int w = threadIdx.x >> 6, lane = threadIdx.x & 63;
  const long long row = (long long)blockIdx.x * 4 + w;
  const float* pr = Sc + row * cS + lane * 8;
  float4 a = *(const float4*)pr;
  float4 b = *(const float4*)(pr + 4);
  float e[8] = {a.x, a.y, a.z, a.w, b.x, b.y, b.z, b.w};
  float m = e[0];
#pragma unroll
  for (int q = 1; q < 8; ++q) m = fmaxf(m, e[q]);
  m = wmax(m);
  float s = 0.f;
#pragma unroll
  for (int q = 0; q < 8; ++q) { e[q] = expf(e[q] - m); s += e[q]; }
  s = wsum(s);
  const float inv = 1.0f / s;
  unsigned h[4], mm[4];
#pragma unroll
  for (int q = 0; q < 4; ++q) {
    unsigned short h0, m0s, h1, m1s;
    split2(e[2 * q] * inv, h0, m0s);
    split2(e[2 * q + 1] * inv, h1, m1s);
    h[q] = (unsigned)h0 | ((unsigned)h1 << 16);
    mm[q] = (unsigned)m0s | ((unsigned)m1s << 16);
  }
  const long long o = row * cS + lane * 8;
  *(uint4*)&P[o] = *(const uint4*)h;
  *(uint4*)&P[pPS + o] = *(const uint4*)mm;
}

// out = LN(ra + rb*rowscale)*g + be ; one WAVE per row (16 elem/lane),
// barrier-free; optional bf16 copy, dual-fp16 copy, fused MoE gate.
__global__ __launch_bounds__(256) void addln_kernel(
    const float* __restrict__ ra, const float* __restrict__ rb,
    const float* __restrict__ rowscale,
    const float* __restrict__ g, const float* __restrict__ be,
    float* __restrict__ out, unsigned short* __restrict__ out16,
    unsigned short* __restrict__ out2p,
    int gate_on, const int* __restrict__ idxes,
    const float* __restrict__ gw, const float* __restrict__ gb,
    int* __restrict__ gate_idx, float* __restrict__ gate_val, int* __restrict__ counts)
{
  const int w = threadIdx.x >> 6, lane = threadIdx.x & 63;
  const int row = blockIdx.x * 4 + w;
  const long long base = (long long)row * cD + lane * 16;
  const float sc = rowscale ? rowscale[row] : 1.0f;
  float v[16];
#pragma unroll
  for (int q = 0; q < 4; ++q) {
    float4 a = *(const float4*)(ra + base + q * 4);
    float4 b = *(const float4*)(rb + base + q * 4);
    v[q * 4 + 0] = a.x + b.x * sc; v[q * 4 + 1] = a.y + b.y * sc;
    v[q * 4 + 2] = a.z + b.z * sc; v[q * 4 + 3] = a.w + b.w * sc;
  }
  float s = 0.f;
#pragma unroll
  for (int q = 0; q < 16; ++q) s += v[q];
  const float mu = wsum(s) * (1.0f / cD);
  float vp = 0.f;
#pragma unroll
  for (int q = 0; q < 16; ++q) { float c = v[q] - mu; vp += c * c; }
  const float rstd = 1.0f / sqrtf(wsum(vp) * (1.0f / cD) + 1e-5f);
  float x[16];
#pragma unroll
  for (int q = 0; q < 4; ++q) {
    float4 gv = *(const float4*)(g + lane * 16 + q * 4);
    float4 bv = *(const float4*)(be + lane * 16 + q * 4);
    x[q * 4 + 0] = (v[q * 4 + 0] - mu) * rstd * gv.x + bv.x;
    x[q * 4 + 1] = (v[q * 4 + 1] - mu) * rstd * gv.y + bv.y;
    x[q * 4 + 2] = (v[q * 4 + 2] - mu) * rstd * gv.z + bv.z;
    x[q * 4 + 3] = (v[q * 4 + 3] - mu) * rstd * gv.w + bv.w;
  }
  if (out) {
#pragma unroll
    for (int q = 0; q < 4; ++q) {
      float4 o; o.x = x[q * 4]; o.y = x[q * 4 + 1]; o.z = x[q * 4 + 2]; o.w = x[q * 4 + 3];
      *(float4*)(out + base + q * 4) = o;
    }
  }
  if (out16) {
    unsigned u[8];
#pragma unroll
    for (int q = 0; q < 8; ++q)
      u[q] = (unsigned)f2b_rne(x[2 * q]) | ((unsigned)f2b_rne(x[2 * q + 1]) << 16);
    *(uint4*)&out16[base] = *(const uint4*)&u[0];
    *(uint4*)&out16[base + 8] = *(const uint4*)&u[4];
  }
  if (out2p) {
    unsigned uh[8], um[8];
#pragma unroll
    for (int q = 0; q < 8; ++q) {
      unsigned short h0, m0s, h1, m1s;
      split2(x[2 * q], h0, m0s);
      split2(x[2 * q + 1], h1, m1s);
      uh[q] = (unsigned)h0 | ((unsigned)h1 << 16);
      um[q] = (unsigned)m0s | ((unsigned)m1s << 16);
    }
    *(uint4*)&out2p[base] = *(const uint4*)&uh[0];
    *(uint4*)&out2p[base + 8] = *(const uint4*)&uh[4];
    *(uint4*)&out2p[TD + base] = *(const uint4*)&um[0];
    *(uint4*)&out2p[TD + base + 8] = *(const uint4*)&um[4];
  }
  if (gate_on) {
    const int ds = idxes[row >> 9];
    const float* gwr = gw + (long long)ds * (cE * cD) + lane * 16;
    float glog[8];
#pragma unroll
    for (int e = 0; e < 8; ++e) {
      float pe = 0.f;
#pragma unroll
      for (int q = 0; q < 4; ++q) {
        float4 wv = *(const float4*)(gwr + e * cD + q * 4);
        pe += x[q * 4] * wv.x + x[q * 4 + 1] * wv.y + x[q * 4 + 2] * wv.z + x[q * 4 + 3] * wv.w;
      }
      glog[e] = wsum(pe);
    }
    if (lane == 0) {
      float m = glog[0] + gb[ds * cE];
      int arg = 0;
      float gl[8];
      gl[0] = m;
#pragma unroll
      for (int e = 1; e < 8; ++e) {
        gl[e] = glog[e] + gb[ds * cE + e];
        if (gl[e] > m) { m = gl[e]; arg = e; }
      }
      float ssum = 0.f;
#pragma unroll
      for (int e = 0; e < 8; ++e) ssum += expf(gl[e] - m);
      gate_idx[row] = arg;
      gate_val[row] = 1.0f / ssum;
      atomicAdd(&counts[arg], 1);
    }
  }
}

// 4 fp32 weight tensors (n elems each) -> fp16 planes, planes-major for q,k,v:
// [q_h|k_h|v_h|q_m|k_m|v_m|o_h|o_m]; tensor 0 scaled by sc0
__global__ __launch_bounds__(256) void conv2x4(
    const float* s0, const float* s1, const float* s2, const float* s3,
    unsigned short* dst, int n, float sc0)
{
  const int wsel = blockIdx.y;
  const float* s = (wsel == 0) ? s0 : (wsel == 1) ? s1 : (wsel == 2) ? s2 : s3;
  const float sc = (wsel == 0) ? sc0 : 1.0f;
  unsigned short* dh = dst + (long long)(wsel < 3 ? wsel : 6) * n;
  unsigned short* dm = dh + (long long)(wsel < 3 ? 3 : 1) * n;
  const long long i = ((long long)blockIdx.x * 256 + threadIdx.x) * 4;
  if (i >= n) return;
  float4 v = *(const float4*)(s + i);
  float vv[4] = {v.x * sc, v.y * sc, v.z * sc, v.w * sc};
  unsigned short h[4], m[4];
#pragma unroll
  for (int q = 0; q < 4; ++q) split2(vv[q], h[q], m[q]);
  uint2 u;
  u.x = (unsigned)h[0] | ((unsigned)h[1] << 16); u.y = (unsigned)h[2] | ((unsigned)h[3] << 16);
  *(uint2*)&dh[i] = u;
  u.x = (unsigned)m[0] | ((unsigned)m[1] << 16); u.y = (unsigned)m[2] | ((unsigned)m[3] << 16);
  *(uint2*)&dm[i] = u;
}

// fp32 activations -> 2-plane fp16 (plane stride n)
__global__ __launch_bounds__(256) void conv2p(const float* __restrict__ s,
                                              unsigned short* __restrict__ d, long long n)
{
  const long long i = ((long long)blockIdx.x * 256 + threadIdx.x) * 4;
  if (i >= n) return;
  float4 v = *(const float4*)(s + i);
  unsigned short h[4], m[4];
  split2(v.x, h[0], m[0]); split2(v.y, h[1], m[1]);
  split2(v.z, h[2], m[2]); split2(v.w, h[3], m[3]);
  uint2 u;
  u.x = (unsigned)h[0] | ((unsigned)h[1] << 16); u.y = (unsigned)h[2] | ((unsigned)h[3] << 16);
  *(uint2*)&d[i] = u;
  u.x = (unsigned)m[0] | ((unsigned)m[1] << 16); u.y = (unsigned)m[2] | ((unsigned)m[3] << 16);
  *(uint2*)&d[n + i] = u;
}

__global__ __launch_bounds__(256) void conv1(const float* __restrict__ s,
                                             unsigned short* __restrict__ d, long long n)
{
  const long long i = ((long long)blockIdx.x * 256 + threadIdx.x) * 4;
  if (i >= n) return;
  float4 v = *(const float4*)(s + i);
  uint2 u;
  u.x = (unsigned)f2b_rne(v.x) | ((unsigned)f2b_rne(v.y) << 16);
  u.y = (unsigned)f2b_rne(v.z) | ((unsigned)f2b_rne(v.w) << 16);
  *(uint2*)&d[i] = u;
}

// [sa_qb*0.125, sa_kb, sa_vb, ca_qb*0.125, ca_kb, ca_vb] -> 6*cD floats
__global__ void prep_bias(const float* a0, const float* a1, const float* a2,
                          const float* b0, const float* b1, const float* b2,
                          float* dst)
{
  const int i = blockIdx.x * 256 + threadIdx.x;
  const int seg = i >> 10, off = i & 1023;
  const float* srcs[6] = {a0, a1, a2, b0, b1, b2};
  const float sc = (seg == 0 || seg == 3) ? 0.125f : 1.0f;
  dst[i] = srcs[seg][off] * sc;
}

__global__ void scan_kernel(const int* __restrict__ counts, int* __restrict__ offsets,
                            int* __restrict__ cursor)
{
  if (threadIdx.x == 0 && blockIdx.x == 0) {
    int a = 0;
    for (int e = 0; e < cE; ++e) { offsets[e] = a; cursor[e] = a; a += counts[e]; }
    offsets[cE] = a;
  }
}

__global__ __launch_bounds__(256) void scatter_kernel(
    const int* __restrict__ gate_idx, int* __restrict__ cursor, int* __restrict__ token_list)
{
  int t = blockIdx.x * 256 + threadIdx.x;
  if (t < cT) {
    int e = gate_idx[t];
    int slot = atomicAdd(&cursor[e], 1);
    token_list[slot] = t;
  }
}

extern "C" void kernel_launch(void* const* d_in, const int* in_sizes, int n_in,
                              void* d_out, int out_size, void* d_ws, size_t ws_size,
                              hipStream_t stream)
{
  (void)in_sizes; (void)n_in; (void)out_size;
  const float* hidden  = (const float*)d_in[0];
  const float* encoder = (const float*)d_in[1];
  const int*   idxes   = (const int*)d_in[2];
  const float* sa_qw = (const float*)d_in[3];
  const float* sa_qb = (const float*)d_in[4];
  const float* sa_kw = (const float*)d_in[5];
  const float* sa_kb = (const float*)d_in[6];
  const float* sa_vw = (const float*)d_in[7];
  const float* sa_vb = (const float*)d_in[8];
  const float* sa_ow = (const float*)d_in[9];
  const float* sa_ob = (const float*)d_in[10];
  const float* ca_qw = (const float*)d_in[11];
  const float* ca_qb = (const float*)d_in[12];
  const float* ca_kw = (const float*)d_in[13];
  const float* ca_kb = (const float*)d_in[14];
  const float* ca_vw = (const float*)d_in[15];
  const float* ca_vb = (const float*)d_in[16];
  const float* ca_ow = (const float*)d_in[17];
  const float* ca_ob = (const float*)d_in[18];
  const float* sa_ln_g = (const float*)d_in[19];
  const float* sa_ln_b = (const float*)d_in[20];
  const float* ca_ln_g = (const float*)d_in[21];
  const float* ca_ln_b = (const float*)d_in[22];
  const float* fin_ln_g = (const float*)d_in[23];
  const float* fin_ln_b = (const float*)d_in[24];
  const float* fc1_w = (const float*)d_in[25];
  const float* fc1_b = (const float*)d_in[26];
  const float* fc2_w = (const float*)d_in[27];
  const float* fc2_b = (const float*)d_in[28];
  const float* exp1_w = (const float*)d_in[29];
  const float* exp1_b = (const float*)d_in[30];
  const float* exp2_w = (const float*)d_in[31];
  const float* gate_w = (const float*)d_in[32];
  const float* gate_b = (const float*)d_in[33];
  float* out = (float*)d_out;

  // ---- workspace layout ----
  size_t off = 0;
  auto alloc = [&](size_t bytes) {
    void* p = (char*)d_ws + off;
    off += (bytes + 255) & ~(size_t)255;
    return p;
  };
  unsigned short* wbuf = (unsigned short*)alloc(4ll * 2 * WW * 2);   // 16 MB (weights)
  unsigned short* QKVs = (unsigned short*)alloc(4ll * 2 * TD * 2);   // 64 MB (Q,K,V,VT/A16 slots)
  unsigned short* attnO16 = (unsigned short*)alloc(2ll * TD * 2);    // 16 MB (O dual-fp16 / hsa16)
  float* hsa   = (float*)alloc(TD * 4);                              // 16 MB
  float* biasb = (float*)alloc(6 * cD * 4);
  float* gate_val = (float*)alloc(cT * 4);
  int* gate_idx   = (int*)alloc(cT * 4);
  int* token_list = (int*)alloc(cT * 4);
  int* ctl        = (int*)alloc(64 * 4);
  int* counts  = ctl;
  int* offsets = ctl + 16;
  int* cursor  = ctl + 32;
  const size_t off_x = off;
  float* xbuf = (float*)alloc(TD * 4);                               // 16 MB (score region start)
  unsigned short* x16 = (unsigned short*)alloc(TD * 2);              // 8 MB

  // score region = [off_x .. ws end), live only during attention phases
  long long region_bytes = (long long)ws_size - (long long)off_x;
  long long perz = (long long)cS * cS * 8;     // 4B scores + 2*2B P planes
  int ZB = (int)(region_bytes / perz);
  if (ZB < 1) ZB = 1;
  if (ZB > 128) ZB = 128;
  float* scoresF = (float*)((char*)d_ws + off_x);
  unsigned short* Pp = (unsigned short*)((char*)d_ws + off_x + (long long)ZB * cS * cS * 4);
  const long long pPS = (long long)ZB * cS * cS;

  // aliases (disjoint lifetimes):
  unsigned short* A16 = QKVs + 6 * TD;                 // slot 3: hidden16/enc16, later VT
  unsigned short* hsa16 = attnO16;                     // dual-fp16 of hsa (post-SA, pre-CA-attn)
  float* OdeltaF = (float*)QKVs;                       // 16 MB (slot 0), after attention
  unsigned short* h2 = QKVs;                           // 8 MB  (MoE phase)
  float* moeF = (float*)(QKVs + 2 * WW * 4);           // 16 MB at QKVs+16MB
  unsigned short* h1 = QKVs + 16ll * WW;               // 32 MB at QKVs+32MB (full fc1 out)

  dim3 blk(256), blk512(512);
  hipMemsetAsync(counts, 0, cE * sizeof(int), stream);
  prep_bias<<<dim3(24), blk, 0, stream>>>(sa_qb, sa_kb, sa_vb, ca_qb, ca_kb, ca_vb, biasb);

  auto attention = [&]() {
    for (int zb = 0; zb < 128; zb += ZB) {
      int zc = 128 - zb; if (zc > ZB) zc = ZB;
      // S = Q @ K^T
      mgemm2<64, 256, 4, 1, 0><<<dim3(8, 2, zc), blk, 0, stream>>>(
          QKVs + (long long)zb * (cS * cDH), TD, (long long)cS * cDH, cDH,
          QKVs + 2 * TD + (long long)zb * (cS * cDH), TD, (long long)cS * cDH, cDH,
          nullptr, scoresF, (long long)cS * cS, cS, cDH, 1.0f, 0);
      softmax2<<<dim3(zc * cS / 4), blk, 0, stream>>>(scoresF, Pp, pPS);
      // O = P @ V   (V^T at slot 3: [B,D,S]) -> dual-fp16 [B,S,D]
      mgemm2<128, 64, 4, 2, 5><<<dim3(4, 1, zc), blk, 0, stream>>>(
          Pp, pPS, (long long)cS * cS, cS,
          QKVs + 6 * TD + (long long)zb * (cDH * cS), TD, (long long)cDH * cS, cS,
          nullptr, attnO16, TD, 0, cS, 1.0f, zb);
    }
  };

  // ================= self-attention =================
  conv2x4<<<dim3(1024, 4), blk, 0, stream>>>(sa_qw, sa_kw, sa_vw, sa_ow, wbuf, (int)WW, 0.125f);
  conv2p<<<dim3(4096), blk, 0, stream>>>(hidden, A16, TD);
  // fused QKV: N=3072 planes-major weights, one balanced 512-block launch
  mgemm2<128, 192, 8, 2, 4><<<dim3(32, 16, 1), blk512, 0, stream>>>(
      A16, TD, 0, cD, wbuf, 3 * WW, 0, cD,
      biasb, QKVs, 0, 0, cD, 1.0f, 0);
  transposeV<<<dim3(4, 128, 2), blk, 0, stream>>>(QKVs + 4 * TD, QKVs + 6 * TD);
  attention();
  mgemm2<128, 128, 4, 2, 0><<<dim3(32, 8, 1), blk, 0, stream>>>(
      attnO16, TD, 0, cD, wbuf + 6ll * WW, WW, 0, cD,
      sa_ob, OdeltaF, 0, cD, cD, 1.0f, 0);
  addln_kernel<<<dim3(cT / 4), blk, 0, stream>>>(
      hidden, OdeltaF, nullptr, sa_ln_g, sa_ln_b, hsa, nullptr, hsa16,
      0, nullptr, nullptr, nullptr, nullptr, nullptr, nullptr);

  // ================= cross-attention =================
  conv2x4<<<dim3(1024, 4), blk, 0, stream>>>(ca_qw, ca_kw, ca_vw, ca_ow, wbuf, (int)WW, 0.125f);
  mgemm2<128, 128, 4, 2, 4><<<dim3(32, 8, 1), blk, 0, stream>>>(
      hsa16, TD, 0, cD, wbuf, 3 * WW, 0, cD,
      biasb + 3 * cD, QKVs, 0, 0, cD, 1.0f, 0);
  conv2p<<<dim3(4096), blk, 0, stream>>>(encoder, A16, TD);
  // fused KV: N=2048 (k,v rows contiguous in planes-major layout)
  mgemm2<128, 128, 4, 2, 4><<<dim3(32, 16, 1), blk, 0, stream>>>(
      A16, TD, 0, cD, wbuf + WW, 3 * WW, 0, cD,
      biasb + 4 * cD, QKVs, 0, 0, cD, 1.0f, 1);
  transposeV<<<dim3(4, 128, 2), blk, 0, stream>>>(QKVs + 4 * TD, QKVs + 6 * TD);
  attention();
  mgemm2<128, 128, 4, 2, 0><<<dim3(32, 8, 1), blk, 0, stream>>>(
      attnO16, TD, 0, cD, wbuf + 6ll * WW, WW, 0, cD,
      ca_ob, OdeltaF, 0, cD, cD, 1.0f, 0);
  addln_kernel<<<dim3(cT / 4), blk, 0, stream>>>(
      hsa, OdeltaF, nullptr, ca_ln_g, ca_ln_b, xbuf, x16, nullptr,
      1, idxes, gate_w, gate_b, gate_idx, gate_val, counts);

  // ================= MoE FFN =================
  scan_kernel<<<dim3(1), dim3(64), 0, stream>>>(counts, offsets, cursor);
  scatter_kernel<<<dim3(16), blk, 0, stream>>>(gate_idx, cursor, token_list);

  unsigned short* wfc1 = wbuf;
  unsigned short* wfc2 = wbuf + 4194304;
  conv1<<<dim3(4096), blk, 0, stream>>>(fc1_w, wfc1, 4194304);
  conv1<<<dim3(4096), blk, 0, stream>>>(fc2_w, wfc2, 4194304);
  mgemm1<0><<<dim3(32, 32), blk, 0, stream>>>(
      x16, cD, wfc1, 0, cD, fc1_b, 0,
      h1, cF1, cD, 1, 1, 0, nullptr, nullptr);
  mgemm1<0><<<dim3(32, 8), blk, 0, stream>>>(
      h1, cF1, wfc2, 0, cF1, fc2_b, 0,
      moeF, cD, cF1, 0, 0, 0, nullptr, nullptr);
  conv1<<<dim3(8192), blk, 0, stream>>>(exp1_w, wbuf, 8388608);
  mgemm1<1><<<dim3(8, 8, 32), blk, 0, stream>>>(
      x16, cD, wbuf, (long long)cI * cD, cD, exp1_b, cI,
      h2, cI, cD, 1, 1, 0, token_list, offsets);
  conv1<<<dim3(8192), blk, 0, stream>>>(exp2_w, wbuf, 8388608);
  mgemm1<1><<<dim3(8, 8, 32), blk, 0, stream>>>(
      h2, cI, wbuf, (long long)cD * cI, cI, nullptr, 0,
      moeF, cD, cI, 0, 0, 1, token_list, offsets);

  addln_kernel<<<dim3(cT / 4), blk, 0, stream>>>(
      xbuf, moeF, gate_val, fin_ln_g, fin_ln_b, out, nullptr, nullptr,
      0, nullptr, nullptr, nullptr, nullptr, nullptr, nullptr);
}